// Round 4
// baseline (134.149 us; speedup 1.0000x reference)
//
#include <hip/hip_runtime.h>

// ---------------------------------------------------------------------------
// Attention block, MI355X bf16-MFMA implementation.  R4:
//  - QKV GEMM: 256x256 8-wave, 4-slot ring (BK=32) RESTRUCTURED into
//    m201-style phases: per K-tile 2 phases x {ds_read -> stage -> barrier ->
//    16 MFMA} with B-frag reuse, counted vmcnt(8) at tile boundary only.
//  - everything else identical to R3 (isolation).
// ---------------------------------------------------------------------------

typedef __bf16 bf16;
typedef __bf16 bf16x4 __attribute__((ext_vector_type(4)));
typedef __bf16 bf16x8 __attribute__((ext_vector_type(8)));
typedef float f32x4 __attribute__((ext_vector_type(4)));

constexpr int S = 3072;
constexpr int DIM = 1280;
constexpr int H = 16;
constexpr int HD = 80;
constexpr int DP = 96;          // padded head dim for QK (multiple of 32)
constexpr int NQKV = 3 * DIM;   // 3840

// log2(e) / sqrt(80): folded into Q so scores are in exp2 domain.
constexpr float QSCALE = 1.4426950408889634f / 8.94427190999916f;

__device__ __forceinline__ void gload_lds16(const void* g, void* l) {
  __builtin_amdgcn_global_load_lds(
      (const __attribute__((address_space(1))) void*)g,
      (__attribute__((address_space(3))) void*)l, 16, 0, 0);
}

// --------------------------- fp32 -> bf16 convert ---------------------------
constexpr long CN1 = (long)S * DIM;       // x
constexpr long CN2 = (long)NQKV * DIM;    // w_qkv

__global__ __launch_bounds__(256) void cvt3(
    const float* __restrict__ x, const float* __restrict__ wq,
    const float* __restrict__ wp, bf16* __restrict__ xo,
    bf16* __restrict__ wqo, bf16* __restrict__ wpo) {
  long i = ((long)blockIdx.x * 256 + threadIdx.x) * 4;
  const float* s;
  bf16* d;
  if (i < CN1) { s = x + i; d = xo + i; }
  else if (i < CN1 + CN2) { s = wq + (i - CN1); d = wqo + (i - CN1); }
  else { s = wp + (i - CN1 - CN2); d = wpo + (i - CN1 - CN2); }
  float4 v = *(const float4*)s;
  bf16x4 o = {(bf16)v.x, (bf16)v.y, (bf16)v.z, (bf16)v.w};
  *(bf16x4*)d = o;
}

// --------------------------- 256^2 ring-buffer GEMM, phased -----------------
// C[m][n] = sum_k A[m][k]*B[n][k] + bias[n].  BM=BN=256, BK=32, 8 waves (2x4),
// 4-slot LDS ring (128 KB).  Per K-tile: 2 phases x {ds_read(4-8 b128) ->
// stage 2 gload_lds -> barrier -> setprio 16 MFMA -> barrier}.  B frags read
// in phase 0 and reused in phase 1.  vmcnt(8) gate once per tile boundary.
// LDS swizzle: involution  a ^= ((a>>7)&7)<<4  (2-way max, measured 0 confl).
template <bool OUT_BF16>
__global__ __launch_bounds__(512, 2) void gemm256(
    const bf16* __restrict__ A, const bf16* __restrict__ B,
    const float* __restrict__ bias, void* __restrict__ Cout, int M, int N,
    int K) {
  extern __shared__ char lds[];  // 4 slots * (16KB A + 16KB B) = 128 KB
  const int tid = threadIdx.x;
  const int w = tid >> 6, lane = tid & 63;
  const int r15 = lane & 15, b4 = lane >> 4;
  const int wr = w >> 2, wc = w & 3;  // 2 x 4 wave grid
  // bijective XCD swizzle
  const int nwg = gridDim.x * gridDim.y;
  const int orig = blockIdx.y * gridDim.x + blockIdx.x;
  const int xcd = orig % 8, loc = orig / 8;
  const int qq = nwg / 8, rq = nwg % 8;
  const int swzid =
      (xcd < rq ? xcd * (qq + 1) : rq * (qq + 1) + (xcd - rq) * qq) + loc;
  const int n0 = (swzid % gridDim.x) * 256, m0 = (swzid / gridDim.x) * 256;
  // staging: per thread 2 A-chunks + 2 B-chunks of 16B per slice; LDS dest is
  // linear, global source pre-swizzled with the read involution.
  const bf16* aSrc[2];
  const bf16* bSrc[2];
  int linv[2];
#pragma unroll
  for (int i = 0; i < 2; i++) {
    const int lin = tid * 16 + i * 8192;
    linv[i] = lin;
    const int logi = lin ^ (((lin >> 7) & 7) << 4);
    const int row = logi >> 6, col = (logi & 63) >> 1;
    aSrc[i] = A + (size_t)(m0 + row) * K + col;
    bSrc[i] = B + (size_t)(n0 + row) * K + col;
  }
  const int NT = K / 32;
  auto stageA = [&](int kt) {
    char* s = lds + (kt & 3) * 32768;
#pragma unroll
    for (int i = 0; i < 2; i++) gload_lds16(aSrc[i] + kt * 32, s + linv[i]);
  };
  auto stageB = [&](int kt) {
    char* s = lds + (kt & 3) * 32768 + 16384;
#pragma unroll
    for (int i = 0; i < 2; i++) gload_lds16(bSrc[i] + kt * 32, s + linv[i]);
  };
  f32x4 acc[8][4] = {};
  stageA(0); stageB(0); stageA(1); stageB(1); stageA(2); stageB(2);
  asm volatile("s_waitcnt vmcnt(8)" ::: "memory");  // slice 0 landed
  __builtin_amdgcn_s_barrier();
  for (int kt = 0; kt < NT; ++kt) {
    const char* As = lds + (kt & 3) * 32768;
    const char* Bs = As + 16384;
    const bool pf = (kt + 3 < NT);
    bf16x8 afr[4], bfr[4];
    // ---- phase 0: A-half 0 + all B frags ----
#pragma unroll
    for (int i = 0; i < 4; i++) {
      int a = (wr * 128 + i * 16 + r15) * 64 + b4 * 16;
      a ^= ((a >> 7) & 7) << 4;
      afr[i] = *(const bf16x8*)(As + a);
    }
#pragma unroll
    for (int j = 0; j < 4; j++) {
      int a = (wc * 64 + j * 16 + r15) * 64 + b4 * 16;
      a ^= ((a >> 7) & 7) << 4;
      bfr[j] = *(const bf16x8*)(Bs + a);
    }
    if (pf) stageA(kt + 3);
    asm volatile("" ::: "memory");
    __builtin_amdgcn_s_barrier();
    __builtin_amdgcn_s_setprio(1);
#pragma unroll
    for (int i = 0; i < 4; i++)
#pragma unroll
      for (int j = 0; j < 4; j++)
        acc[i][j] = __builtin_amdgcn_mfma_f32_16x16x32_bf16(afr[i], bfr[j],
                                                            acc[i][j], 0, 0, 0);
    __builtin_amdgcn_s_setprio(0);
    asm volatile("" ::: "memory");
    __builtin_amdgcn_s_barrier();
    // ---- phase 1: A-half 1, reuse B frags ----
#pragma unroll
    for (int i = 0; i < 4; i++) {
      int a = (wr * 128 + 64 + i * 16 + r15) * 64 + b4 * 16;
      a ^= ((a >> 7) & 7) << 4;
      afr[i] = *(const bf16x8*)(As + a);
    }
    if (pf) stageB(kt + 3);
    asm volatile("" ::: "memory");
    __builtin_amdgcn_s_barrier();
    __builtin_amdgcn_s_setprio(1);
#pragma unroll
    for (int i = 0; i < 4; i++)
#pragma unroll
      for (int j = 0; j < 4; j++)
        acc[4 + i][j] = __builtin_amdgcn_mfma_f32_16x16x32_bf16(
            afr[i], bfr[j], acc[4 + i][j], 0, 0, 0);
    __builtin_amdgcn_s_setprio(0);
    // gate: slice kt+1 must be resident before next tile's phase-0 reads.
    const int rem = NT - 2 - kt;
    if (rem >= 2)      asm volatile("s_waitcnt vmcnt(8)" ::: "memory");
    else if (rem == 1) asm volatile("s_waitcnt vmcnt(4)" ::: "memory");
    else if (rem == 0) asm volatile("s_waitcnt vmcnt(0)" ::: "memory");
    else               asm volatile("" ::: "memory");
    __builtin_amdgcn_s_barrier();
  }
#pragma unroll
  for (int j = 0; j < 4; j++) {
    const int n = n0 + wc * 64 + j * 16 + r15;
    const float bv = bias[n];
#pragma unroll
    for (int i = 0; i < 8; i++) {
      const int mr = m0 + wr * 128 + i * 16 + b4 * 4;
#pragma unroll
      for (int r = 0; r < 4; r++) {
        float v = acc[i][j][r] + bv;
        if (OUT_BF16)
          ((bf16*)Cout)[(size_t)(mr + r) * N + n] = (bf16)v;
        else
          ((float*)Cout)[(size_t)(mr + r) * N + n] = v;
      }
    }
  }
}

// --------------------------- 128^2 2-phase GEMM (proj) ----------------------
template <bool OUT_BF16>
__global__ __launch_bounds__(256) void gemm_bt(
    const bf16* __restrict__ A, const bf16* __restrict__ B,
    const float* __restrict__ bias, void* __restrict__ Cout, int M, int N,
    int K) {
  __shared__ bf16 Al[2][128 * 32];
  __shared__ bf16 Bl[2][128 * 32];
  const int tid = threadIdx.x;
  const int w = tid >> 6, lane = tid & 63;
  const int r15 = lane & 15, b4 = lane >> 4;
  const int nwg = gridDim.x * gridDim.y;
  const int orig = blockIdx.y * gridDim.x + blockIdx.x;
  const int swzid = (orig & 7) * (nwg >> 3) + (orig >> 3);
  const int bx = swzid % gridDim.x, by = swzid / gridDim.x;
  const int m0 = by * 128, n0 = bx * 128;
  const int wm = (w >> 1) * 64, wn = (w & 1) * 64;
  f32x4 acc[4][4] = {};
  const int row0 = tid >> 2, ko0 = (tid & 3) * 8;
  const bf16* Ar0 = A + (size_t)(m0 + row0) * K + ko0;
  const bf16* Ar1 = A + (size_t)(m0 + row0 + 64) * K + ko0;
  const bf16* Br0 = B + (size_t)(n0 + row0) * K + ko0;
  const bf16* Br1 = B + (size_t)(n0 + row0 + 64) * K + ko0;

  auto stage = [&](int buf, int k0) {
    char* la = (char*)Al[buf] + w * 1024;
    char* lb = (char*)Bl[buf] + w * 1024;
    gload_lds16(Ar0 + k0, la);
    gload_lds16(Ar1 + k0, la + 4096);
    gload_lds16(Br0 + k0, lb);
    gload_lds16(Br1 + k0, lb + 4096);
  };

  stage(0, 0);
  int cur = 0;
  for (int k0 = 0; k0 < K; k0 += 32) {
    __syncthreads();
    if (k0 + 32 < K) stage(cur ^ 1, k0 + 32);
    bf16x8 af[4], bfr[4];
#pragma unroll
    for (int i = 0; i < 4; i++) {
      af[i] = *(const bf16x8*)((const char*)Al[cur] + (wm + i * 16 + r15) * 64 + b4 * 16);
      bfr[i] = *(const bf16x8*)((const char*)Bl[cur] + (wn + i * 16 + r15) * 64 + b4 * 16);
    }
#pragma unroll
    for (int i = 0; i < 4; i++)
#pragma unroll
      for (int j = 0; j < 4; j++)
        acc[i][j] = __builtin_amdgcn_mfma_f32_16x16x32_bf16(af[i], bfr[j], acc[i][j], 0, 0, 0);
    cur ^= 1;
  }
#pragma unroll
  for (int j = 0; j < 4; j++) {
    const int n = n0 + wn + j * 16 + r15;
    const float bv = bias[n];
#pragma unroll
    for (int i = 0; i < 4; i++) {
      const int mr = m0 + wm + i * 16 + b4 * 4;
#pragma unroll
      for (int r = 0; r < 4; r++) {
        float v = acc[i][j][r] + bv;
        if (OUT_BF16)
          ((bf16*)Cout)[(size_t)(mr + r) * N + n] = (bf16)v;
        else
          ((float*)Cout)[(size_t)(mr + r) * N + n] = v;
      }
    }
  }
}

// --------------------------- RoPE + scatter (vectorized) --------------------
__global__ __launch_bounds__(256) void rope_scatter(
    const bf16* __restrict__ qkv, const float* __restrict__ rp,
    bf16* __restrict__ Qo, bf16* __restrict__ Ko, bf16* __restrict__ VTo) {
  __shared__ bf16 vl[80][72];  // [d][row] transpose buffer (pad 72)
  const int h = blockIdx.x / 48, st = blockIdx.x % 48;
  const int tid = threadIdx.x;
#pragma unroll
  for (int c = 0; c < 3; c++) {
    int ch = c * 256 + tid;
    if (ch < 640) {
      int row = ch / 10, ck = ch % 10;
      int s = st * 64 + row;
      bf16x8 v = *(const bf16x8*)(qkv + (size_t)s * NQKV + 2 * DIM + h * HD + ck * 8);
#pragma unroll
      for (int e = 0; e < 8; e++) vl[ck * 8 + e][row] = v[e];
    }
  }
#pragma unroll
  for (int c = 0; c < 3; c++) {
    int ch = c * 256 + tid;
    if (ch < 640) {
      int row = ch / 10, t10 = ch % 10;
      int which = t10 >= 5 ? 1 : 0, cp = t10 % 5;
      int s = st * 64 + row;
      const bf16* src = qkv + (size_t)s * NQKV + which * DIM + h * HD;
      bf16x8 lo = *(const bf16x8*)(src + cp * 8);
      bf16x8 hi = *(const bf16x8*)(src + 40 + cp * 8);
      const float* rr = rp + (size_t)s * 40 + cp * 8;
      float4 a0 = *(const float4*)rr;
      float4 a1 = *(const float4*)(rr + 4);
      float ang[8] = {a0.x, a0.y, a0.z, a0.w, a1.x, a1.y, a1.z, a1.w};
      const float sc = which ? 1.0f : QSCALE;
      bf16x8 olo, ohi;
#pragma unroll
      for (int e = 0; e < 8; e++) {
        float sn, cs;
        __sincosf(ang[e], &sn, &cs);
        float t1 = (float)lo[e], t2 = (float)hi[e];
        olo[e] = (bf16)((t1 * cs - t2 * sn) * sc);
        ohi[e] = (bf16)((t2 * cs + t1 * sn) * sc);
      }
      bf16* dst = (which ? Ko : Qo) + ((size_t)h * S + s) * DP;
      *(bf16x8*)(dst + cp * 8) = olo;
      *(bf16x8*)(dst + 40 + cp * 8) = ohi;
    }
  }
  {
    int row = tid >> 2, slot = tid & 3;
    int s = st * 64 + row;
    bf16* dst = ((slot >> 1) ? Ko : Qo) + ((size_t)h * S + s) * DP + 80 + (slot & 1) * 8;
    bf16x8 z = {};
    *(bf16x8*)dst = z;
  }
  __syncthreads();
#pragma unroll
  for (int c = 0; c < 3; c++) {
    int ch = c * 256 + tid;
    if (ch < 640) {
      int d = ch >> 3, slot = ch & 7;
      *(bf16x8*)(VTo + (size_t)(h * HD + d) * S + st * 64 + slot * 8) =
          *(const bf16x8*)(&vl[d][slot * 8]);
    }
  }
}

// --------------------------- flash attention --------------------------------
__global__ __launch_bounds__(256) void attn_kern(
    const bf16* __restrict__ Qg, const bf16* __restrict__ Kg,
    const bf16* __restrict__ Vg, const int* __restrict__ cu, int nseg,
    bf16* __restrict__ Out) {
  __shared__ bf16 Kl[2][64 * 128];   // [key][d], 256B rows, XOR-swizzled
  __shared__ bf16 Vl[2][80 * 64];    // [d][key], 128B rows, XOR-swizzled
  __shared__ bf16 Pl[4][16 * 64];    // per wave [q][key], swizzled
  const int tid = threadIdx.x, w = tid >> 6, lane = tid & 63;
  const int r15 = lane & 15, b4 = lane >> 4;
  const int nwg = gridDim.x;  // 768, multiple of 8
  const int orig = blockIdx.x;
  const int swzb = (orig & 7) * (nwg >> 3) + (orig >> 3);
  const int h = swzb / 48, qt = swzb % 48;
  const int q = qt * 64 + w * 16 + r15;
  int sq = 0, eq = S, lo = 0, hi = S;
  {
    const int qlo = qt * 64, qhi = qt * 64 + 63;
#pragma unroll
    for (int i = 0; i < 8; i++) {
      if (i >= nseg) break;
      int a = cu[i], b = cu[i + 1];
      if (q >= a && q < b) { sq = a; eq = b; }
      if (qlo >= a && qlo < b) lo = a;
      if (qhi >= a && qhi < b) hi = b;
    }
  }
  const int swz = (r15 & 7) << 4;
  bf16x8 qf[3];
  {
    const bf16* qrow = Qg + ((size_t)h * S + q) * DP + b4 * 8;
#pragma unroll
    for (int c = 0; c < 3; c++) qf[c] = *(const bf16x8*)(qrow + c * 32);
  }
  f32x4 o[5] = {};
  float m = -1e30f, l = 0.f;
  const bf16* Kbase = Kg + (size_t)h * S * DP;
  const bf16* Vbase = Vg + (size_t)h * HD * S;

  int krow[3], kslot[3], vd[3], vslot[3];
#pragma unroll
  for (int c = 0; c < 3; c++) {
    int ch = c * 256 + tid;
    krow[c] = ch / 12; kslot[c] = ch % 12;
    vd[c] = ch >> 3;   vslot[c] = ch & 7;
  }
  bf16x8 kreg[3], vreg[3];

  auto load_stage = [&](int k0) {
#pragma unroll
    for (int c = 0; c < 3; c++)
      kreg[c] = *(const bf16x8*)(Kbase + (size_t)(k0 + krow[c]) * DP + kslot[c] * 8);
#pragma unroll
    for (int c = 0; c < 3; c++)
      if (c < 2 || tid < 128)
        vreg[c] = *(const bf16x8*)(Vbase + (size_t)vd[c] * S + k0 + vslot[c] * 8);
  };
  auto write_stage = [&](int buf) {
#pragma unroll
    for (int c = 0; c < 3; c++)
      *(bf16x8*)((char*)Kl[buf] +
                 ((krow[c] * 256 + kslot[c] * 16) ^ ((krow[c] & 7) << 4))) = kreg[c];
#pragma unroll
    for (int c = 0; c < 3; c++)
      if (c < 2 || tid < 128)
        *(bf16x8*)((char*)Vl[buf] +
                   ((vd[c] * 128 + vslot[c] * 16) ^ ((vd[c] & 7) << 4))) = vreg[c];
  };

  const int k0start = lo & ~63;
  load_stage(k0start);
  write_stage(0);
  __syncthreads();
  int cur = 0;
  for (int k0 = k0start; k0 < hi; k0 += 64) {
    const bool more = (k0 + 64 < hi);
    if (more) load_stage(k0 + 64);
    f32x4 st[4] = {};
    __builtin_amdgcn_s_setprio(1);
#pragma unroll
    for (int g = 0; g < 4; g++)
#pragma unroll
      for (int c = 0; c < 3; c++) {
        bf16x8 kf = *(const bf16x8*)((const char*)Kl[cur] +
                                     (((g * 16 + r15) * 256 + c * 64 + b4 * 16) ^ swz));
        st[g] = __builtin_amdgcn_mfma_f32_16x16x32_bf16(kf, qf[c], st[g], 0, 0, 0);
      }
    __builtin_amdgcn_s_setprio(0);
    float sv[16];
    float tm = -3e38f;
    if (k0 >= sq && k0 + 63 < eq) {
#pragma unroll
      for (int g = 0; g < 4; g++)
#pragma unroll
        for (int r = 0; r < 4; r++) {
          sv[g * 4 + r] = st[g][r];
          tm = fmaxf(tm, st[g][r]);
        }
    } else {
#pragma unroll
      for (int g = 0; g < 4; g++)
#pragma unroll
        for (int r = 0; r < 4; r++) {
          int key = k0 + g * 16 + b4 * 4 + r;
          float sc = (key >= sq && key < eq) ? st[g][r] : -1e30f;
          sv[g * 4 + r] = sc;
          tm = fmaxf(tm, sc);
        }
    }
    tm = fmaxf(tm, __shfl_xor(tm, 16));
    tm = fmaxf(tm, __shfl_xor(tm, 32));
    if (!__all(tm <= m + 8.f)) {
      const float mn = fmaxf(m, tm);
      const float alpha = __builtin_amdgcn_exp2f(m - mn);
#pragma unroll
      for (int dg = 0; dg < 5; dg++) o[dg] *= alpha;
      l *= alpha;
      m = mn;
    }
    float rs = 0.f;
#pragma unroll
    for (int g = 0; g < 4; g++) {
      bf16x4 pp;
#pragma unroll
      for (int r = 0; r < 4; r++) {
        float p = __builtin_amdgcn_exp2f(sv[g * 4 + r] - m);
        rs += p;
        pp[r] = (bf16)p;
      }
      *(bf16x4*)((char*)Pl[w] + ((r15 * 128 + g * 32 + b4 * 8) ^ swz)) = pp;
    }
    rs += __shfl_xor(rs, 16);
    rs += __shfl_xor(rs, 32);
    l += rs;
    __builtin_amdgcn_s_setprio(1);
#pragma unroll
    for (int dg = 0; dg < 5; dg++)
#pragma unroll
      for (int c = 0; c < 2; c++) {
        bf16x8 vf = *(const bf16x8*)((const char*)Vl[cur] +
                                     (((dg * 16 + r15) * 128 + c * 64 + b4 * 16) ^ swz));
        bf16x8 pf = *(const bf16x8*)((const char*)Pl[w] +
                                     ((r15 * 128 + c * 64 + b4 * 16) ^ swz));
        o[dg] = __builtin_amdgcn_mfma_f32_16x16x32_bf16(vf, pf, o[dg], 0, 0, 0);
      }
    __builtin_amdgcn_s_setprio(0);
    if (more) write_stage(cur ^ 1);
    __syncthreads();
    cur ^= 1;
  }
  const float inv = 1.f / l;
  bf16* orow = Out + (size_t)q * DIM + h * HD + b4 * 4;
#pragma unroll
  for (int dg = 0; dg < 5; dg++) {
    bf16x4 ov = {(bf16)(o[dg][0] * inv), (bf16)(o[dg][1] * inv),
                 (bf16)(o[dg][2] * inv), (bf16)(o[dg][3] * inv)};
    *(bf16x4*)(orow + dg * 16) = ov;
  }
}

// --------------------------- launch -----------------------------------------
extern "C" void kernel_launch(void* const* d_in, const int* in_sizes, int n_in,
                              void* d_out, int out_size, void* d_ws,
                              size_t ws_size, hipStream_t stream) {
  const float* x = (const float*)d_in[0];
  const int* cu = (const int*)d_in[1];
  const float* rope = (const float*)d_in[2];
  const float* w_qkv = (const float*)d_in[3];
  const float* b_qkv = (const float*)d_in[4];
  const float* w_proj = (const float*)d_in[5];
  const float* b_proj = (const float*)d_in[6];
  const int nseg = in_sizes[1] - 1;

  bf16* x16 = (bf16*)d_ws;
  bf16* wq16 = x16 + (size_t)S * DIM;
  bf16* wp16 = wq16 + (size_t)NQKV * DIM;
  bf16* qkv16 = wp16 + (size_t)DIM * DIM;
  bf16* Qb = qkv16 + (size_t)S * NQKV;
  bf16* Kb = Qb + (size_t)H * S * DP;
  bf16* VTb = Kb + (size_t)H * S * DP;
  bf16* attn16 = VTb + (size_t)H * HD * S;

  cvt3<<<10240, 256, 0, stream>>>(x, w_qkv, w_proj, x16, wq16, wp16);
  gemm256<true><<<dim3(NQKV / 256, S / 256), 512, 131072, stream>>>(
      x16, wq16, b_qkv, qkv16, S, NQKV, DIM);
  rope_scatter<<<H * 48, 256, 0, stream>>>(qkv16, rope, Qb, Kb, VTb);
  attn_kern<<<H * 48, 256, 0, stream>>>(Qb, Kb, VTb, cu, nseg, attn16);
  gemm_bt<false><<<dim3(DIM / 128, S / 128), 256, 0, stream>>>(
      attn16, wp16, b_proj, d_out, S, DIM, DIM);
}

// Round 5
// 133.418 us; speedup vs baseline: 1.0055x; 1.0055x over previous
//
#include <hip/hip_runtime.h>

// ---------------------------------------------------------------------------
// Attention block, MI355X bf16-MFMA implementation.  R5:
//  - NEW pack_inputs kernel: writes x -> packA and w_qkv -> packB as the exact
//    per-K-slice 16KB LDS images (swizzle baked in).  QKV GEMM staging is now
//    fully linear: each global_load_lds reads 1KB contiguous global memory.
//  - gemm256 compute loop / attn / rope / proj unchanged (isolation).
// ---------------------------------------------------------------------------

typedef __bf16 bf16;
typedef __bf16 bf16x4 __attribute__((ext_vector_type(4)));
typedef __bf16 bf16x8 __attribute__((ext_vector_type(8)));
typedef float f32x4 __attribute__((ext_vector_type(4)));

constexpr int S = 3072;
constexpr int DIM = 1280;
constexpr int H = 16;
constexpr int HD = 80;
constexpr int DP = 96;          // padded head dim for QK (multiple of 32)
constexpr int NQKV = 3 * DIM;   // 3840

constexpr int MB_A = S / 256;    // 12 m-blocks
constexpr int NB_B = NQKV / 256; // 15 n-blocks
constexpr int NKT = DIM / 32;    // 40 K-slices

// log2(e) / sqrt(80): folded into Q so scores are in exp2 domain.
constexpr float QSCALE = 1.4426950408889634f / 8.94427190999916f;

__device__ __forceinline__ void gload_lds16(const void* g, void* l) {
  __builtin_amdgcn_global_load_lds(
      (const __attribute__((address_space(1))) void*)g,
      (__attribute__((address_space(3))) void*)l, 16, 0, 0);
}

// --------------------------- input packing ----------------------------------
// packA[mb][kt] = 16KB image: byte lin holds A[mb*256 + ((lin^swz)>>6)]
//                 [kt*32 + (((lin^swz)&63)>>1)], swz = ((lin>>7)&7)<<4.
// packB likewise from w_qkv rows.  wp16 = linear bf16 of w_proj.
constexpr long PA_CHUNKS = (long)MB_A * NKT * 1024;  // 491520 16B chunks
constexpr long PB_CHUNKS = (long)NB_B * NKT * 1024;  // 614400
constexpr long PW_CHUNKS = (long)DIM * DIM / 8;      // 204800

__global__ __launch_bounds__(256) void pack_inputs(
    const float* __restrict__ x, const float* __restrict__ wq,
    const float* __restrict__ wp, bf16* __restrict__ pA,
    bf16* __restrict__ pB, bf16* __restrict__ wp16) {
  long t = (long)blockIdx.x * 256 + threadIdx.x;
  const float* src;
  bf16* dst;
  if (t < PA_CHUNKS + PB_CHUNKS) {
    int blk, rem;
    const float* base;
    bf16* obase;
    if (t < PA_CHUNKS) {
      blk = (int)(t / (NKT * 1024)); rem = (int)(t % (NKT * 1024));
      base = x; obase = pA + t * 8;
    } else {
      long t2 = t - PA_CHUNKS;
      blk = (int)(t2 / (NKT * 1024)); rem = (int)(t2 % (NKT * 1024));
      base = wq; obase = pB + t2 * 8;
    }
    const int kt = rem >> 10, c = rem & 1023;
    const int lin = c * 16;
    const int logi = lin ^ (((lin >> 7) & 7) << 4);
    const int row = logi >> 6, col = (logi & 63) >> 1;
    src = base + (size_t)(blk * 256 + row) * DIM + kt * 32 + col;
    dst = obase;
  } else {
    long t2 = t - PA_CHUNKS - PB_CHUNKS;
    src = wp + t2 * 8;
    dst = wp16 + t2 * 8;
  }
  float4 v0 = *(const float4*)src;
  float4 v1 = *(const float4*)(src + 4);
  bf16x8 o = {(bf16)v0.x, (bf16)v0.y, (bf16)v0.z, (bf16)v0.w,
              (bf16)v1.x, (bf16)v1.y, (bf16)v1.z, (bf16)v1.w};
  *(bf16x8*)dst = o;
}

// --------------------------- 256^2 ring-buffer GEMM, packed -----------------
// C[m][n] = sum_k A[m][k]*B[n][k] + bias[n] from PRE-PACKED panels.
// BM=BN=256, BK=32, 8 waves (2x4), 4-slot LDS ring (128 KB), per K-tile
// 2 phases x {ds_read -> stage(1KB-linear gload_lds) -> barrier -> 16 MFMA},
// counted vmcnt(8) at tile boundary.  Read swizzle matches pack layout.
template <bool OUT_BF16>
__global__ __launch_bounds__(512, 2) void gemm256(
    const bf16* __restrict__ pA, const bf16* __restrict__ pB,
    const float* __restrict__ bias, void* __restrict__ Cout, int M, int N,
    int K) {
  extern __shared__ char lds[];  // 4 slots * (16KB A + 16KB B) = 128 KB
  const int tid = threadIdx.x;
  const int w = tid >> 6, lane = tid & 63;
  const int r15 = lane & 15, b4 = lane >> 4;
  const int wr = w >> 2, wc = w & 3;  // 2 x 4 wave grid
  // bijective XCD swizzle
  const int nwg = gridDim.x * gridDim.y;
  const int orig = blockIdx.y * gridDim.x + blockIdx.x;
  const int xcd = orig % 8, loc = orig / 8;
  const int qq = nwg / 8, rq = nwg % 8;
  const int swzid =
      (xcd < rq ? xcd * (qq + 1) : rq * (qq + 1) + (xcd - rq) * qq) + loc;
  const int nb = swzid % gridDim.x, mb = swzid / gridDim.x;
  const int n0 = nb * 256, m0 = mb * 256;
  const char* aPanel = (const char*)pA + (size_t)mb * NKT * 16384;
  const char* bPanel = (const char*)pB + (size_t)nb * NKT * 16384;
  const int NT = K / 32;
  auto stageA = [&](int kt) {
    char* s = lds + (kt & 3) * 32768;
    const char* g = aPanel + (size_t)kt * 16384;
    gload_lds16(g + tid * 16, s + tid * 16);
    gload_lds16(g + 8192 + tid * 16, s + 8192 + tid * 16);
  };
  auto stageB = [&](int kt) {
    char* s = lds + (kt & 3) * 32768 + 16384;
    const char* g = bPanel + (size_t)kt * 16384;
    gload_lds16(g + tid * 16, s + tid * 16);
    gload_lds16(g + 8192 + tid * 16, s + 8192 + tid * 16);
  };
  f32x4 acc[8][4] = {};
  stageA(0); stageB(0); stageA(1); stageB(1); stageA(2); stageB(2);
  asm volatile("s_waitcnt vmcnt(8)" ::: "memory");  // slice 0 landed
  __builtin_amdgcn_s_barrier();
  for (int kt = 0; kt < NT; ++kt) {
    const char* As = lds + (kt & 3) * 32768;
    const char* Bs = As + 16384;
    const bool pf = (kt + 3 < NT);
    bf16x8 afr[4], bfr[4];
    // ---- phase 0: A-half 0 + all B frags ----
#pragma unroll
    for (int i = 0; i < 4; i++) {
      int a = (wr * 128 + i * 16 + r15) * 64 + b4 * 16;
      a ^= ((a >> 7) & 7) << 4;
      afr[i] = *(const bf16x8*)(As + a);
    }
#pragma unroll
    for (int j = 0; j < 4; j++) {
      int a = (wc * 64 + j * 16 + r15) * 64 + b4 * 16;
      a ^= ((a >> 7) & 7) << 4;
      bfr[j] = *(const bf16x8*)(Bs + a);
    }
    if (pf) stageA(kt + 3);
    asm volatile("" ::: "memory");
    __builtin_amdgcn_s_barrier();
    __builtin_amdgcn_s_setprio(1);
#pragma unroll
    for (int i = 0; i < 4; i++)
#pragma unroll
      for (int j = 0; j < 4; j++)
        acc[i][j] = __builtin_amdgcn_mfma_f32_16x16x32_bf16(afr[i], bfr[j],
                                                            acc[i][j], 0, 0, 0);
    __builtin_amdgcn_s_setprio(0);
    asm volatile("" ::: "memory");
    __builtin_amdgcn_s_barrier();
    // ---- phase 1: A-half 1, reuse B frags ----
#pragma unroll
    for (int i = 0; i < 4; i++) {
      int a = (wr * 128 + 64 + i * 16 + r15) * 64 + b4 * 16;
      a ^= ((a >> 7) & 7) << 4;
      afr[i] = *(const bf16x8*)(As + a);
    }
    if (pf) stageB(kt + 3);
    asm volatile("" ::: "memory");
    __builtin_amdgcn_s_barrier();
    __builtin_amdgcn_s_setprio(1);
#pragma unroll
    for (int i = 0; i < 4; i++)
#pragma unroll
      for (int j = 0; j < 4; j++)
        acc[4 + i][j] = __builtin_amdgcn_mfma_f32_16x16x32_bf16(
            afr[i], bfr[j], acc[4 + i][j], 0, 0, 0);
    __builtin_amdgcn_s_setprio(0);
    // gate: slice kt+1 must be resident before next tile's phase-0 reads.
    const int rem = NT - 2 - kt;
    if (rem >= 2)      asm volatile("s_waitcnt vmcnt(8)" ::: "memory");
    else if (rem == 1) asm volatile("s_waitcnt vmcnt(4)" ::: "memory");
    else if (rem == 0) asm volatile("s_waitcnt vmcnt(0)" ::: "memory");
    else               asm volatile("" ::: "memory");
    __builtin_amdgcn_s_barrier();
  }
#pragma unroll
  for (int j = 0; j < 4; j++) {
    const int n = n0 + wc * 64 + j * 16 + r15;
    const float bv = bias[n];
#pragma unroll
    for (int i = 0; i < 8; i++) {
      const int mr = m0 + wr * 128 + i * 16 + b4 * 4;
#pragma unroll
      for (int r = 0; r < 4; r++) {
        float v = acc[i][j][r] + bv;
        if (OUT_BF16)
          ((bf16*)Cout)[(size_t)(mr + r) * N + n] = (bf16)v;
        else
          ((float*)Cout)[(size_t)(mr + r) * N + n] = v;
      }
    }
  }
}

// --------------------------- 128^2 2-phase GEMM (proj) ----------------------
template <bool OUT_BF16>
__global__ __launch_bounds__(256) void gemm_bt(
    const bf16* __restrict__ A, const bf16* __restrict__ B,
    const float* __restrict__ bias, void* __restrict__ Cout, int M, int N,
    int K) {
  __shared__ bf16 Al[2][128 * 32];
  __shared__ bf16 Bl[2][128 * 32];
  const int tid = threadIdx.x;
  const int w = tid >> 6, lane = tid & 63;
  const int r15 = lane & 15, b4 = lane >> 4;
  const int nwg = gridDim.x * gridDim.y;
  const int orig = blockIdx.y * gridDim.x + blockIdx.x;
  const int swzid = (orig & 7) * (nwg >> 3) + (orig >> 3);
  const int bx = swzid % gridDim.x, by = swzid / gridDim.x;
  const int m0 = by * 128, n0 = bx * 128;
  const int wm = (w >> 1) * 64, wn = (w & 1) * 64;
  f32x4 acc[4][4] = {};
  const int row0 = tid >> 2, ko0 = (tid & 3) * 8;
  const bf16* Ar0 = A + (size_t)(m0 + row0) * K + ko0;
  const bf16* Ar1 = A + (size_t)(m0 + row0 + 64) * K + ko0;
  const bf16* Br0 = B + (size_t)(n0 + row0) * K + ko0;
  const bf16* Br1 = B + (size_t)(n0 + row0 + 64) * K + ko0;

  auto stage = [&](int buf, int k0) {
    char* la = (char*)Al[buf] + w * 1024;
    char* lb = (char*)Bl[buf] + w * 1024;
    gload_lds16(Ar0 + k0, la);
    gload_lds16(Ar1 + k0, la + 4096);
    gload_lds16(Br0 + k0, lb);
    gload_lds16(Br1 + k0, lb + 4096);
  };

  stage(0, 0);
  int cur = 0;
  for (int k0 = 0; k0 < K; k0 += 32) {
    __syncthreads();
    if (k0 + 32 < K) stage(cur ^ 1, k0 + 32);
    bf16x8 af[4], bfr[4];
#pragma unroll
    for (int i = 0; i < 4; i++) {
      af[i] = *(const bf16x8*)((const char*)Al[cur] + (wm + i * 16 + r15) * 64 + b4 * 16);
      bfr[i] = *(const bf16x8*)((const char*)Bl[cur] + (wn + i * 16 + r15) * 64 + b4 * 16);
    }
#pragma unroll
    for (int i = 0; i < 4; i++)
#pragma unroll
      for (int j = 0; j < 4; j++)
        acc[i][j] = __builtin_amdgcn_mfma_f32_16x16x32_bf16(af[i], bfr[j], acc[i][j], 0, 0, 0);
    cur ^= 1;
  }
#pragma unroll
  for (int j = 0; j < 4; j++) {
    const int n = n0 + wn + j * 16 + r15;
    const float bv = bias[n];
#pragma unroll
    for (int i = 0; i < 4; i++) {
      const int mr = m0 + wm + i * 16 + b4 * 4;
#pragma unroll
      for (int r = 0; r < 4; r++) {
        float v = acc[i][j][r] + bv;
        if (OUT_BF16)
          ((bf16*)Cout)[(size_t)(mr + r) * N + n] = (bf16)v;
        else
          ((float*)Cout)[(size_t)(mr + r) * N + n] = v;
      }
    }
  }
}

// --------------------------- RoPE + scatter (vectorized) --------------------
__global__ __launch_bounds__(256) void rope_scatter(
    const bf16* __restrict__ qkv, const float* __restrict__ rp,
    bf16* __restrict__ Qo, bf16* __restrict__ Ko, bf16* __restrict__ VTo) {
  __shared__ bf16 vl[80][72];  // [d][row] transpose buffer (pad 72)
  const int h = blockIdx.x / 48, st = blockIdx.x % 48;
  const int tid = threadIdx.x;
#pragma unroll
  for (int c = 0; c < 3; c++) {
    int ch = c * 256 + tid;
    if (ch < 640) {
      int row = ch / 10, ck = ch % 10;
      int s = st * 64 + row;
      bf16x8 v = *(const bf16x8*)(qkv + (size_t)s * NQKV + 2 * DIM + h * HD + ck * 8);
#pragma unroll
      for (int e = 0; e < 8; e++) vl[ck * 8 + e][row] = v[e];
    }
  }
#pragma unroll
  for (int c = 0; c < 3; c++) {
    int ch = c * 256 + tid;
    if (ch < 640) {
      int row = ch / 10, t10 = ch % 10;
      int which = t10 >= 5 ? 1 : 0, cp = t10 % 5;
      int s = st * 64 + row;
      const bf16* src = qkv + (size_t)s * NQKV + which * DIM + h * HD;
      bf16x8 lo = *(const bf16x8*)(src + cp * 8);
      bf16x8 hi = *(const bf16x8*)(src + 40 + cp * 8);
      const float* rr = rp + (size_t)s * 40 + cp * 8;
      float4 a0 = *(const float4*)rr;
      float4 a1 = *(const float4*)(rr + 4);
      float ang[8] = {a0.x, a0.y, a0.z, a0.w, a1.x, a1.y, a1.z, a1.w};
      const float sc = which ? 1.0f : QSCALE;
      bf16x8 olo, ohi;
#pragma unroll
      for (int e = 0; e < 8; e++) {
        float sn, cs;
        __sincosf(ang[e], &sn, &cs);
        float t1 = (float)lo[e], t2 = (float)hi[e];
        olo[e] = (bf16)((t1 * cs - t2 * sn) * sc);
        ohi[e] = (bf16)((t2 * cs + t1 * sn) * sc);
      }
      bf16* dst = (which ? Ko : Qo) + ((size_t)h * S + s) * DP;
      *(bf16x8*)(dst + cp * 8) = olo;
      *(bf16x8*)(dst + 40 + cp * 8) = ohi;
    }
  }
  {
    int row = tid >> 2, slot = tid & 3;
    int s = st * 64 + row;
    bf16* dst = ((slot >> 1) ? Ko : Qo) + ((size_t)h * S + s) * DP + 80 + (slot & 1) * 8;
    bf16x8 z = {};
    *(bf16x8*)dst = z;
  }
  __syncthreads();
#pragma unroll
  for (int c = 0; c < 3; c++) {
    int ch = c * 256 + tid;
    if (ch < 640) {
      int d = ch >> 3, slot = ch & 7;
      *(bf16x8*)(VTo + (size_t)(h * HD + d) * S + st * 64 + slot * 8) =
          *(const bf16x8*)(&vl[d][slot * 8]);
    }
  }
}

// --------------------------- flash attention --------------------------------
__global__ __launch_bounds__(256) void attn_kern(
    const bf16* __restrict__ Qg, const bf16* __restrict__ Kg,
    const bf16* __restrict__ Vg, const int* __restrict__ cu, int nseg,
    bf16* __restrict__ Out) {
  __shared__ bf16 Kl[2][64 * 128];   // [key][d], 256B rows, XOR-swizzled
  __shared__ bf16 Vl[2][80 * 64];    // [d][key], 128B rows, XOR-swizzled
  __shared__ bf16 Pl[4][16 * 64];    // per wave [q][key], swizzled
  const int tid = threadIdx.x, w = tid >> 6, lane = tid & 63;
  const int r15 = lane & 15, b4 = lane >> 4;
  const int nwg = gridDim.x;  // 768, multiple of 8
  const int orig = blockIdx.x;
  const int swzb = (orig & 7) * (nwg >> 3) + (orig >> 3);
  const int h = swzb / 48, qt = swzb % 48;
  const int q = qt * 64 + w * 16 + r15;
  int sq = 0, eq = S, lo = 0, hi = S;
  {
    const int qlo = qt * 64, qhi = qt * 64 + 63;
#pragma unroll
    for (int i = 0; i < 8; i++) {
      if (i >= nseg) break;
      int a = cu[i], b = cu[i + 1];
      if (q >= a && q < b) { sq = a; eq = b; }
      if (qlo >= a && qlo < b) lo = a;
      if (qhi >= a && qhi < b) hi = b;
    }
  }
  const int swz = (r15 & 7) << 4;
  bf16x8 qf[3];
  {
    const bf16* qrow = Qg + ((size_t)h * S + q) * DP + b4 * 8;
#pragma unroll
    for (int c = 0; c < 3; c++) qf[c] = *(const bf16x8*)(qrow + c * 32);
  }
  f32x4 o[5] = {};
  float m = -1e30f, l = 0.f;
  const bf16* Kbase = Kg + (size_t)h * S * DP;
  const bf16* Vbase = Vg + (size_t)h * HD * S;

  int krow[3], kslot[3], vd[3], vslot[3];
#pragma unroll
  for (int c = 0; c < 3; c++) {
    int ch = c * 256 + tid;
    krow[c] = ch / 12; kslot[c] = ch % 12;
    vd[c] = ch >> 3;   vslot[c] = ch & 7;
  }
  bf16x8 kreg[3], vreg[3];

  auto load_stage = [&](int k0) {
#pragma unroll
    for (int c = 0; c < 3; c++)
      kreg[c] = *(const bf16x8*)(Kbase + (size_t)(k0 + krow[c]) * DP + kslot[c] * 8);
#pragma unroll
    for (int c = 0; c < 3; c++)
      if (c < 2 || tid < 128)
        vreg[c] = *(const bf16x8*)(Vbase + (size_t)vd[c] * S + k0 + vslot[c] * 8);
  };
  auto write_stage = [&](int buf) {
#pragma unroll
    for (int c = 0; c < 3; c++)
      *(bf16x8*)((char*)Kl[buf] +
                 ((krow[c] * 256 + kslot[c] * 16) ^ ((krow[c] & 7) << 4))) = kreg[c];
#pragma unroll
    for (int c = 0; c < 3; c++)
      if (c < 2 || tid < 128)
        *(bf16x8*)((char*)Vl[buf] +
                   ((vd[c] * 128 + vslot[c] * 16) ^ ((vd[c] & 7) << 4))) = vreg[c];
  };

  const int k0start = lo & ~63;
  load_stage(k0start);
  write_stage(0);
  __syncthreads();
  int cur = 0;
  for (int k0 = k0start; k0 < hi; k0 += 64) {
    const bool more = (k0 + 64 < hi);
    if (more) load_stage(k0 + 64);
    f32x4 st[4] = {};
    __builtin_amdgcn_s_setprio(1);
#pragma unroll
    for (int g = 0; g < 4; g++)
#pragma unroll
      for (int c = 0; c < 3; c++) {
        bf16x8 kf = *(const bf16x8*)((const char*)Kl[cur] +
                                     (((g * 16 + r15) * 256 + c * 64 + b4 * 16) ^ swz));
        st[g] = __builtin_amdgcn_mfma_f32_16x16x32_bf16(kf, qf[c], st[g], 0, 0, 0);
      }
    __builtin_amdgcn_s_setprio(0);
    float sv[16];
    float tm = -3e38f;
    if (k0 >= sq && k0 + 63 < eq) {
#pragma unroll
      for (int g = 0; g < 4; g++)
#pragma unroll
        for (int r = 0; r < 4; r++) {
          sv[g * 4 + r] = st[g][r];
          tm = fmaxf(tm, st[g][r]);
        }
    } else {
#pragma unroll
      for (int g = 0; g < 4; g++)
#pragma unroll
        for (int r = 0; r < 4; r++) {
          int key = k0 + g * 16 + b4 * 4 + r;
          float sc = (key >= sq && key < eq) ? st[g][r] : -1e30f;
          sv[g * 4 + r] = sc;
          tm = fmaxf(tm, sc);
        }
    }
    tm = fmaxf(tm, __shfl_xor(tm, 16));
    tm = fmaxf(tm, __shfl_xor(tm, 32));
    if (!__all(tm <= m + 8.f)) {
      const float mn = fmaxf(m, tm);
      const float alpha = __builtin_amdgcn_exp2f(m - mn);
#pragma unroll
      for (int dg = 0; dg < 5; dg++) o[dg] *= alpha;
      l *= alpha;
      m = mn;
    }
    float rs = 0.f;
#pragma unroll
    for (int g = 0; g < 4; g++) {
      bf16x4 pp;
#pragma unroll
      for (int r = 0; r < 4; r++) {
        float p = __builtin_amdgcn_exp2f(sv[g * 4 + r] - m);
        rs += p;
        pp[r] = (bf16)p;
      }
      *(bf16x4*)((char*)Pl[w] + ((r15 * 128 + g * 32 + b4 * 8) ^ swz)) = pp;
    }
    rs += __shfl_xor(rs, 16);
    rs += __shfl_xor(rs, 32);
    l += rs;
    __builtin_amdgcn_s_setprio(1);
#pragma unroll
    for (int dg = 0; dg < 5; dg++)
#pragma unroll
      for (int c = 0; c < 2; c++) {
        bf16x8 vf = *(const bf16x8*)((const char*)Vl[cur] +
                                     (((dg * 16 + r15) * 128 + c * 64 + b4 * 16) ^ swz));
        bf16x8 pf = *(const bf16x8*)((const char*)Pl[w] +
                                     ((r15 * 128 + c * 64 + b4 * 16) ^ swz));
        o[dg] = __builtin_amdgcn_mfma_f32_16x16x32_bf16(vf, pf, o[dg], 0, 0, 0);
      }
    __builtin_amdgcn_s_setprio(0);
    if (more) write_stage(cur ^ 1);
    __syncthreads();
    cur ^= 1;
  }
  const float inv = 1.f / l;
  bf16* orow = Out + (size_t)q * DIM + h * HD + b4 * 4;
#pragma unroll
  for (int dg = 0; dg < 5; dg++) {
    bf16x4 ov = {(bf16)(o[dg][0] * inv), (bf16)(o[dg][1] * inv),
                 (bf16)(o[dg][2] * inv), (bf16)(o[dg][3] * inv)};
    *(bf16x4*)(orow + dg * 16) = ov;
  }
}

// --------------------------- launch -----------------------------------------
extern "C" void kernel_launch(void* const* d_in, const int* in_sizes, int n_in,
                              void* d_out, int out_size, void* d_ws,
                              size_t ws_size, hipStream_t stream) {
  const float* x = (const float*)d_in[0];
  const int* cu = (const int*)d_in[1];
  const float* rope = (const float*)d_in[2];
  const float* w_qkv = (const float*)d_in[3];
  const float* b_qkv = (const float*)d_in[4];
  const float* w_proj = (const float*)d_in[5];
  const float* b_proj = (const float*)d_in[6];
  const int nseg = in_sizes[1] - 1;

  bf16* pA = (bf16*)d_ws;                          // S*DIM elems (packed)
  bf16* pB = pA + (size_t)S * DIM;                 // NQKV*DIM elems (packed)
  bf16* wp16 = pB + (size_t)NQKV * DIM;
  bf16* qkv16 = wp16 + (size_t)DIM * DIM;
  bf16* Qb = qkv16 + (size_t)S * NQKV;
  bf16* Kb = Qb + (size_t)H * S * DP;
  bf16* VTb = Kb + (size_t)H * S * DP;
  bf16* attn16 = VTb + (size_t)H * HD * S;

  const long total_chunks = PA_CHUNKS + PB_CHUNKS + PW_CHUNKS;  // 1310720
  pack_inputs<<<(int)(total_chunks / 256), 256, 0, stream>>>(
      x, w_qkv, w_proj, pA, pB, wp16);
  gemm256<true><<<dim3(NQKV / 256, S / 256), 512, 131072, stream>>>(
      pA, pB, b_qkv, qkv16, S, NQKV, DIM);
  rope_scatter<<<H * 48, 256, 0, stream>>>(qkv16, rope, Qb, Kb, VTb);
  attn_kern<<<H * 48, 256, 0, stream>>>(Qb, Kb, VTb, cu, nseg, attn16);
  gemm_bt<false><<<dim3(DIM / 128, S / 128), 256, 0, stream>>>(
      attn16, wp16, b_proj, d_out, S, DIM, DIM);
}

// Round 6
// 132.437 us; speedup vs baseline: 1.0129x; 1.0074x over previous
//
#include <hip/hip_runtime.h>

// ---------------------------------------------------------------------------
// Attention block, MI355X bf16-MFMA implementation.  R6:
//  - attn REWRITTEN: 32x32x16 MFMA, 32 q/wave, 4 waves x 128 q per block,
//    P kept in registers (pack + shfl_xor(32) redistribution, zero LDS for P),
//    K LDS [64][128] ((row&15)<<4) swizzle (2-way = free), V^T [96][64],
//    global_load_lds staging with pre-swizzled sources, dbuf.
//  - Q stored DP=80 (packed); K stored DP=128 zero-padded (for linear staging).
//  - pack_inputs / gemm256 / proj gemm_bt unchanged (isolation).
// ---------------------------------------------------------------------------

typedef __bf16 bf16;
typedef __bf16 bf16x4 __attribute__((ext_vector_type(4)));
typedef __bf16 bf16x8 __attribute__((ext_vector_type(8)));
typedef float f32x4 __attribute__((ext_vector_type(4)));
typedef float f32x16 __attribute__((ext_vector_type(16)));
typedef unsigned int u32;

constexpr int S = 3072;
constexpr int DIM = 1280;
constexpr int H = 16;
constexpr int HD = 80;
constexpr int KDP = 128;        // K head-dim padded for linear LDS staging
constexpr int NQKV = 3 * DIM;   // 3840

constexpr int MB_A = S / 256;    // 12 m-blocks
constexpr int NB_B = NQKV / 256; // 15 n-blocks
constexpr int NKT = DIM / 32;    // 40 K-slices

// log2(e) / sqrt(80): folded into Q so scores are in exp2 domain.
constexpr float QSCALE = 1.4426950408889634f / 8.94427190999916f;

__device__ __forceinline__ void gload_lds16(const void* g, void* l) {
  __builtin_amdgcn_global_load_lds(
      (const __attribute__((address_space(1))) void*)g,
      (__attribute__((address_space(3))) void*)l, 16, 0, 0);
}

__device__ __forceinline__ u32 pkbf2(float a, float b) {
  union { bf16 h[2]; u32 w; } u;
  u.h[0] = (bf16)a; u.h[1] = (bf16)b;
  return u.w;
}

// --------------------------- input packing (unchanged) ----------------------
constexpr long PA_CHUNKS = (long)MB_A * NKT * 1024;
constexpr long PB_CHUNKS = (long)NB_B * NKT * 1024;
constexpr long PW_CHUNKS = (long)DIM * DIM / 8;

__global__ __launch_bounds__(256) void pack_inputs(
    const float* __restrict__ x, const float* __restrict__ wq,
    const float* __restrict__ wp, bf16* __restrict__ pA,
    bf16* __restrict__ pB, bf16* __restrict__ wp16) {
  long t = (long)blockIdx.x * 256 + threadIdx.x;
  const float* src;
  bf16* dst;
  if (t < PA_CHUNKS + PB_CHUNKS) {
    int blk, rem;
    const float* base;
    bf16* obase;
    if (t < PA_CHUNKS) {
      blk = (int)(t / (NKT * 1024)); rem = (int)(t % (NKT * 1024));
      base = x; obase = pA + t * 8;
    } else {
      long t2 = t - PA_CHUNKS;
      blk = (int)(t2 / (NKT * 1024)); rem = (int)(t2 % (NKT * 1024));
      base = wq; obase = pB + t2 * 8;
    }
    const int kt = rem >> 10, c = rem & 1023;
    const int lin = c * 16;
    const int logi = lin ^ (((lin >> 7) & 7) << 4);
    const int row = logi >> 6, col = (logi & 63) >> 1;
    src = base + (size_t)(blk * 256 + row) * DIM + kt * 32 + col;
    dst = obase;
  } else {
    long t2 = t - PA_CHUNKS - PB_CHUNKS;
    src = wp + t2 * 8;
    dst = wp16 + t2 * 8;
  }
  float4 v0 = *(const float4*)src;
  float4 v1 = *(const float4*)(src + 4);
  bf16x8 o = {(bf16)v0.x, (bf16)v0.y, (bf16)v0.z, (bf16)v0.w,
              (bf16)v1.x, (bf16)v1.y, (bf16)v1.z, (bf16)v1.w};
  *(bf16x8*)dst = o;
}

// --------------------------- 256^2 ring-buffer GEMM (unchanged) -------------
template <bool OUT_BF16>
__global__ __launch_bounds__(512, 2) void gemm256(
    const bf16* __restrict__ pA, const bf16* __restrict__ pB,
    const float* __restrict__ bias, void* __restrict__ Cout, int M, int N,
    int K) {
  extern __shared__ char lds[];
  const int tid = threadIdx.x;
  const int w = tid >> 6, lane = tid & 63;
  const int r15 = lane & 15, b4 = lane >> 4;
  const int wr = w >> 2, wc = w & 3;
  const int nwg = gridDim.x * gridDim.y;
  const int orig = blockIdx.y * gridDim.x + blockIdx.x;
  const int xcd = orig % 8, loc = orig / 8;
  const int qq = nwg / 8, rq = nwg % 8;
  const int swzid =
      (xcd < rq ? xcd * (qq + 1) : rq * (qq + 1) + (xcd - rq) * qq) + loc;
  const int nb = swzid % gridDim.x, mb = swzid / gridDim.x;
  const int n0 = nb * 256, m0 = mb * 256;
  const char* aPanel = (const char*)pA + (size_t)mb * NKT * 16384;
  const char* bPanel = (const char*)pB + (size_t)nb * NKT * 16384;
  const int NT = K / 32;
  auto stageA = [&](int kt) {
    char* s = lds + (kt & 3) * 32768;
    const char* g = aPanel + (size_t)kt * 16384;
    gload_lds16(g + tid * 16, s + tid * 16);
    gload_lds16(g + 8192 + tid * 16, s + 8192 + tid * 16);
  };
  auto stageB = [&](int kt) {
    char* s = lds + (kt & 3) * 32768 + 16384;
    const char* g = bPanel + (size_t)kt * 16384;
    gload_lds16(g + tid * 16, s + tid * 16);
    gload_lds16(g + 8192 + tid * 16, s + 8192 + tid * 16);
  };
  f32x4 acc[8][4] = {};
  stageA(0); stageB(0); stageA(1); stageB(1); stageA(2); stageB(2);
  asm volatile("s_waitcnt vmcnt(8)" ::: "memory");
  __builtin_amdgcn_s_barrier();
  for (int kt = 0; kt < NT; ++kt) {
    const char* As = lds + (kt & 3) * 32768;
    const char* Bs = As + 16384;
    const bool pf = (kt + 3 < NT);
    bf16x8 afr[4], bfr[4];
#pragma unroll
    for (int i = 0; i < 4; i++) {
      int a = (wr * 128 + i * 16 + r15) * 64 + b4 * 16;
      a ^= ((a >> 7) & 7) << 4;
      afr[i] = *(const bf16x8*)(As + a);
    }
#pragma unroll
    for (int j = 0; j < 4; j++) {
      int a = (wc * 64 + j * 16 + r15) * 64 + b4 * 16;
      a ^= ((a >> 7) & 7) << 4;
      bfr[j] = *(const bf16x8*)(Bs + a);
    }
    if (pf) stageA(kt + 3);
    asm volatile("" ::: "memory");
    __builtin_amdgcn_s_barrier();
    __builtin_amdgcn_s_setprio(1);
#pragma unroll
    for (int i = 0; i < 4; i++)
#pragma unroll
      for (int j = 0; j < 4; j++)
        acc[i][j] = __builtin_amdgcn_mfma_f32_16x16x32_bf16(afr[i], bfr[j],
                                                            acc[i][j], 0, 0, 0);
    __builtin_amdgcn_s_setprio(0);
    asm volatile("" ::: "memory");
    __builtin_amdgcn_s_barrier();
#pragma unroll
    for (int i = 0; i < 4; i++) {
      int a = (wr * 128 + 64 + i * 16 + r15) * 64 + b4 * 16;
      a ^= ((a >> 7) & 7) << 4;
      afr[i] = *(const bf16x8*)(As + a);
    }
    if (pf) stageB(kt + 3);
    asm volatile("" ::: "memory");
    __builtin_amdgcn_s_barrier();
    __builtin_amdgcn_s_setprio(1);
#pragma unroll
    for (int i = 0; i < 4; i++)
#pragma unroll
      for (int j = 0; j < 4; j++)
        acc[4 + i][j] = __builtin_amdgcn_mfma_f32_16x16x32_bf16(
            afr[i], bfr[j], acc[4 + i][j], 0, 0, 0);
    __builtin_amdgcn_s_setprio(0);
    const int rem = NT - 2 - kt;
    if (rem >= 2)      asm volatile("s_waitcnt vmcnt(8)" ::: "memory");
    else if (rem == 1) asm volatile("s_waitcnt vmcnt(4)" ::: "memory");
    else if (rem == 0) asm volatile("s_waitcnt vmcnt(0)" ::: "memory");
    else               asm volatile("" ::: "memory");
    __builtin_amdgcn_s_barrier();
  }
#pragma unroll
  for (int j = 0; j < 4; j++) {
    const int n = n0 + wc * 64 + j * 16 + r15;
    const float bv = bias[n];
#pragma unroll
    for (int i = 0; i < 8; i++) {
      const int mr = m0 + wr * 128 + i * 16 + b4 * 4;
#pragma unroll
      for (int r = 0; r < 4; r++) {
        float v = acc[i][j][r] + bv;
        if (OUT_BF16)
          ((bf16*)Cout)[(size_t)(mr + r) * N + n] = (bf16)v;
        else
          ((float*)Cout)[(size_t)(mr + r) * N + n] = v;
      }
    }
  }
}

// --------------------------- 128^2 2-phase GEMM (proj, unchanged) -----------
template <bool OUT_BF16>
__global__ __launch_bounds__(256) void gemm_bt(
    const bf16* __restrict__ A, const bf16* __restrict__ B,
    const float* __restrict__ bias, void* __restrict__ Cout, int M, int N,
    int K) {
  __shared__ bf16 Al[2][128 * 32];
  __shared__ bf16 Bl[2][128 * 32];
  const int tid = threadIdx.x;
  const int w = tid >> 6, lane = tid & 63;
  const int r15 = lane & 15, b4 = lane >> 4;
  const int nwg = gridDim.x * gridDim.y;
  const int orig = blockIdx.y * gridDim.x + blockIdx.x;
  const int swzid = (orig & 7) * (nwg >> 3) + (orig >> 3);
  const int bx = swzid % gridDim.x, by = swzid / gridDim.x;
  const int m0 = by * 128, n0 = bx * 128;
  const int wm = (w >> 1) * 64, wn = (w & 1) * 64;
  f32x4 acc[4][4] = {};
  const int row0 = tid >> 2, ko0 = (tid & 3) * 8;
  const bf16* Ar0 = A + (size_t)(m0 + row0) * K + ko0;
  const bf16* Ar1 = A + (size_t)(m0 + row0 + 64) * K + ko0;
  const bf16* Br0 = B + (size_t)(n0 + row0) * K + ko0;
  const bf16* Br1 = B + (size_t)(n0 + row0 + 64) * K + ko0;

  auto stage = [&](int buf, int k0) {
    char* la = (char*)Al[buf] + w * 1024;
    char* lb = (char*)Bl[buf] + w * 1024;
    gload_lds16(Ar0 + k0, la);
    gload_lds16(Ar1 + k0, la + 4096);
    gload_lds16(Br0 + k0, lb);
    gload_lds16(Br1 + k0, lb + 4096);
  };

  stage(0, 0);
  int cur = 0;
  for (int k0 = 0; k0 < K; k0 += 32) {
    __syncthreads();
    if (k0 + 32 < K) stage(cur ^ 1, k0 + 32);
    bf16x8 af[4], bfr[4];
#pragma unroll
    for (int i = 0; i < 4; i++) {
      af[i] = *(const bf16x8*)((const char*)Al[cur] + (wm + i * 16 + r15) * 64 + b4 * 16);
      bfr[i] = *(const bf16x8*)((const char*)Bl[cur] + (wn + i * 16 + r15) * 64 + b4 * 16);
    }
#pragma unroll
    for (int i = 0; i < 4; i++)
#pragma unroll
      for (int j = 0; j < 4; j++)
        acc[i][j] = __builtin_amdgcn_mfma_f32_16x16x32_bf16(af[i], bfr[j], acc[i][j], 0, 0, 0);
    cur ^= 1;
  }
#pragma unroll
  for (int j = 0; j < 4; j++) {
    const int n = n0 + wn + j * 16 + r15;
    const float bv = bias[n];
#pragma unroll
    for (int i = 0; i < 4; i++) {
      const int mr = m0 + wm + i * 16 + b4 * 4;
#pragma unroll
      for (int r = 0; r < 4; r++) {
        float v = acc[i][j][r] + bv;
        if (OUT_BF16)
          ((bf16*)Cout)[(size_t)(mr + r) * N + n] = (bf16)v;
        else
          ((float*)Cout)[(size_t)(mr + r) * N + n] = v;
      }
    }
  }
}

// --------------------------- RoPE + scatter ---------------------------------
// qkv16 -> Q[h][s][80] (QSCALE), K[h][s][128] (zero pad 80..127), VT[h][d][S].
__global__ __launch_bounds__(256) void rope_scatter(
    const bf16* __restrict__ qkv, const float* __restrict__ rp,
    bf16* __restrict__ Qo, bf16* __restrict__ Ko, bf16* __restrict__ VTo) {
  __shared__ bf16 vl[80][72];
  const int h = blockIdx.x / 48, st = blockIdx.x % 48;
  const int tid = threadIdx.x;
#pragma unroll
  for (int c = 0; c < 3; c++) {
    int ch = c * 256 + tid;
    if (ch < 640) {
      int row = ch / 10, ck = ch % 10;
      int s = st * 64 + row;
      bf16x8 v = *(const bf16x8*)(qkv + (size_t)s * NQKV + 2 * DIM + h * HD + ck * 8);
#pragma unroll
      for (int e = 0; e < 8; e++) vl[ck * 8 + e][row] = v[e];
    }
  }
#pragma unroll
  for (int c = 0; c < 3; c++) {
    int ch = c * 256 + tid;
    if (ch < 640) {
      int row = ch / 10, t10 = ch % 10;
      int which = t10 >= 5 ? 1 : 0, cp = t10 % 5;
      int s = st * 64 + row;
      const bf16* src = qkv + (size_t)s * NQKV + which * DIM + h * HD;
      bf16x8 lo = *(const bf16x8*)(src + cp * 8);
      bf16x8 hi = *(const bf16x8*)(src + 40 + cp * 8);
      const float* rr = rp + (size_t)s * 40 + cp * 8;
      float4 a0 = *(const float4*)rr;
      float4 a1 = *(const float4*)(rr + 4);
      float ang[8] = {a0.x, a0.y, a0.z, a0.w, a1.x, a1.y, a1.z, a1.w};
      const float sc = which ? 1.0f : QSCALE;
      bf16x8 olo, ohi;
#pragma unroll
      for (int e = 0; e < 8; e++) {
        float sn, cs;
        __sincosf(ang[e], &sn, &cs);
        float t1 = (float)lo[e], t2 = (float)hi[e];
        olo[e] = (bf16)((t1 * cs - t2 * sn) * sc);
        ohi[e] = (bf16)((t2 * cs + t1 * sn) * sc);
      }
      bf16* dst = which ? (Ko + ((size_t)h * S + s) * KDP)
                        : (Qo + ((size_t)h * S + s) * HD);
      *(bf16x8*)(dst + cp * 8) = olo;
      *(bf16x8*)(dst + 40 + cp * 8) = ohi;
    }
  }
  // zero K pad cols [80,128): 64 rows x 6 chunks
#pragma unroll
  for (int c = 0; c < 2; c++) {
    int ch = c * 256 + tid;
    if (ch < 384) {
      int row = ch / 6, cc = ch % 6;
      bf16x8 z = {};
      *(bf16x8*)(Ko + ((size_t)h * S + st * 64 + row) * KDP + 80 + cc * 8) = z;
    }
  }
  __syncthreads();
#pragma unroll
  for (int c = 0; c < 3; c++) {
    int ch = c * 256 + tid;
    if (ch < 640) {
      int d = ch >> 3, slot = ch & 7;
      *(bf16x8*)(VTo + (size_t)(h * HD + d) * S + st * 64 + slot * 8) =
          *(const bf16x8*)(&vl[d][slot * 8]);
    }
  }
}

// --------------------------- flash attention (32x32) ------------------------
// Block: 4 waves x 32 q = 128 q-rows of one head.  Swapped QK^T (lane owns
// q-col), P redistributed in-register via pack + shfl_xor(32).  KV tile 64.
__global__ __launch_bounds__(256) void attn_kern(
    const bf16* __restrict__ Qg, const bf16* __restrict__ Kg,
    const bf16* __restrict__ Vg, const int* __restrict__ cu, int nseg,
    bf16* __restrict__ Out) {
  __shared__ bf16 Kl[2][64 * 128];  // [key][128], 256B rows, ((row&15)<<4) swz
  __shared__ bf16 Vl[2][96 * 64];   // [d][64], 128B rows, ((row&7)<<4) swz
  const int tid = threadIdx.x, w = tid >> 6, lane = tid & 63;
  const int r31 = lane & 31, hi = lane >> 5;
  const int nwg = gridDim.x;  // 384
  const int orig = blockIdx.x;
  const int swzb = (orig & 7) * (nwg >> 3) + (orig >> 3);
  const int h = swzb / 24, qb = swzb % 24;
  const int q = qb * 128 + w * 32 + r31;
  int sq = 0, eq = S, lo = 0, hik = S;
  {
    const int qlo = qb * 128, qhi = qb * 128 + 127;
#pragma unroll
    for (int i = 0; i < 8; i++) {
      if (i >= nseg) break;
      int a = cu[i], b = cu[i + 1];
      if (q >= a && q < b) { sq = a; eq = b; }
      if (qlo >= a && qlo < b) lo = a;
      if (qhi >= a && qhi < b) hik = b;
    }
  }
  // zero V pad rows [80,96) in both buffers
  {
    int b = tid >> 7, o = (tid & 127) * 16;
    bf16x8 z = {};
    *(bf16x8*)((char*)Vl[b] + 10240 + o) = z;
  }
  // Q fragments: B-operand, k = kk*16 + hi*8 + e
  bf16x8 qf[5];
  {
    const bf16* qrow = Qg + ((size_t)h * S + q) * HD + hi * 8;
#pragma unroll
    for (int kk = 0; kk < 5; kk++) qf[kk] = *(const bf16x8*)(qrow + kk * 16);
  }
  // staging geometry
  int kdst[4], ksrc[4], vdst[3], vsrc[3];
#pragma unroll
  for (int c = 0; c < 4; c++) {
    int lin = (c * 256 + tid) * 16;
    int row = lin >> 8, colb = (lin & 255) ^ ((row & 15) << 4);
    kdst[c] = lin; ksrc[c] = row * KDP + colb / 2;
  }
#pragma unroll
  for (int c = 0; c < 3; c++) {
    int lin = (c * 256 + tid) * 16;
    int row = lin >> 7, colb = (lin & 127) ^ ((row & 7) << 4);
    vdst[c] = lin; vsrc[c] = row * S + colb / 2;
  }
  const bf16* Kbase = Kg + (size_t)h * S * KDP;
  const bf16* Vbase = Vg + (size_t)h * HD * S;
  auto stage = [&](int buf, int k0) {
#pragma unroll
    for (int c = 0; c < 4; c++)
      gload_lds16(Kbase + (size_t)k0 * KDP + ksrc[c], (char*)Kl[buf] + kdst[c]);
#pragma unroll
    for (int c = 0; c < 3; c++)
      if (c < 2 || tid < 128)
        gload_lds16(Vbase + vsrc[c] + k0, (char*)Vl[buf] + vdst[c]);
  };
  f32x16 o0 = {}, o1 = {}, o2 = {};
  float m = -1e30f, l = 0.f;
  const int k0s = lo & ~63;
  stage(0, k0s);
  asm volatile("s_waitcnt vmcnt(0)" ::: "memory");
  __syncthreads();
  int cur = 0;
  for (int k0 = k0s; k0 < hik; k0 += 64) {
    const bool more = (k0 + 64 < hik);
    if (more) stage(cur ^ 1, k0 + 64);
    // ---- S^T = K * Q^T  (two 32-key m-tiles) ----
    f32x16 st0 = {}, st1 = {};
    __builtin_amdgcn_s_setprio(1);
#pragma unroll
    for (int kk = 0; kk < 5; kk++) {
      const int colb = kk * 32 + hi * 16;
      bf16x8 kf0 = *(const bf16x8*)((const char*)Kl[cur] +
                                    r31 * 256 + (colb ^ ((r31 & 15) << 4)));
      bf16x8 kf1 = *(const bf16x8*)((const char*)Kl[cur] + (32 + r31) * 256 +
                                    (colb ^ ((r31 & 15) << 4)));
      st0 = __builtin_amdgcn_mfma_f32_32x32x16_bf16(kf0, qf[kk], st0, 0, 0, 0);
      st1 = __builtin_amdgcn_mfma_f32_32x32x16_bf16(kf1, qf[kk], st1, 0, 0, 0);
    }
    __builtin_amdgcn_s_setprio(0);
    // ---- mask + online softmax (exp2 domain) ----
    float tm = -3e38f;
    if (k0 >= sq && k0 + 63 < eq) {
#pragma unroll
      for (int j = 0; j < 16; j++) {
        tm = fmaxf(tm, st0[j]);
        tm = fmaxf(tm, st1[j]);
      }
    } else {
#pragma unroll
      for (int j = 0; j < 16; j++) {
        const int crow = (j & 3) + 8 * (j >> 2) + 4 * hi;
        int key0 = k0 + crow, key1 = k0 + 32 + crow;
        st0[j] = (key0 >= sq && key0 < eq) ? st0[j] : -1e30f;
        st1[j] = (key1 >= sq && key1 < eq) ? st1[j] : -1e30f;
        tm = fmaxf(tm, st0[j]);
        tm = fmaxf(tm, st1[j]);
      }
    }
    tm = fmaxf(tm, __shfl_xor(tm, 32));
    if (!__all(tm <= m + 8.f)) {  // defer-max
      const float mn = fmaxf(m, tm);
      const float alpha = __builtin_amdgcn_exp2f(m - mn);
      o0 *= alpha; o1 *= alpha; o2 *= alpha;
      l *= alpha;
      m = mn;
    }
    // P = exp2(S - m), pack to words wd[mt][g2][h]
    float rs = 0.f;
    u32 wd0[4][2], wd1[4][2];
#pragma unroll
    for (int g2 = 0; g2 < 4; g2++) {
#pragma unroll
      for (int hh = 0; hh < 2; hh++) {
        float a0 = __builtin_amdgcn_exp2f(st0[g2 * 4 + 2 * hh] - m);
        float a1 = __builtin_amdgcn_exp2f(st0[g2 * 4 + 2 * hh + 1] - m);
        float b0 = __builtin_amdgcn_exp2f(st1[g2 * 4 + 2 * hh] - m);
        float b1 = __builtin_amdgcn_exp2f(st1[g2 * 4 + 2 * hh + 1] - m);
        rs += a0 + a1 + b0 + b1;
        wd0[g2][hh] = pkbf2(a0, a1);
        wd1[g2][hh] = pkbf2(b0, b1);
      }
    }
    rs += __shfl_xor(rs, 32);
    l += rs;
    // ---- O^T += V^T * P^T ----
    __builtin_amdgcn_s_setprio(1);
#pragma unroll
    for (int kk = 0; kk < 4; kk++) {
      const int g2o = (kk & 1) * 2 + hi;
      const int g2s = (kk & 1) * 2 + (hi ^ 1);
      u32 own0, own1, snd0, snd1;
      if (kk < 2) {
        own0 = wd0[g2o][0]; own1 = wd0[g2o][1];
        snd0 = wd0[g2s][0]; snd1 = wd0[g2s][1];
      } else {
        own0 = wd1[g2o][0]; own1 = wd1[g2o][1];
        snd0 = wd1[g2s][0]; snd1 = wd1[g2s][1];
      }
      u32 rc0 = (u32)__shfl_xor((int)snd0, 32);
      u32 rc1 = (u32)__shfl_xor((int)snd1, 32);
      union { u32 w[4]; bf16x8 v; } pf;
      if (hi == 0) { pf.w[0] = own0; pf.w[1] = own1; pf.w[2] = rc0; pf.w[3] = rc1; }
      else         { pf.w[0] = rc0;  pf.w[1] = rc1;  pf.w[2] = own0; pf.w[3] = own1; }
      const int colb = kk * 32 + hi * 16;
#pragma unroll
      for (int mt = 0; mt < 3; mt++) {
        const int row = mt * 32 + r31;
        bf16x8 vf = *(const bf16x8*)((const char*)Vl[cur] + row * 128 +
                                     (colb ^ ((row & 7) << 4)));
        f32x16 * op = mt == 0 ? &o0 : (mt == 1 ? &o1 : &o2);
        *op = __builtin_amdgcn_mfma_f32_32x32x16_bf16(vf, pf.v, *op, 0, 0, 0);
      }
    }
    __builtin_amdgcn_s_setprio(0);
    asm volatile("s_waitcnt vmcnt(0)" ::: "memory");
    __syncthreads();
    cur ^= 1;
  }
  // ---- write O: lane owns output row q; d = mt*32 + 8*rg + 4*hi + (0..3) ----
  const float inv = 1.f / l;
  bf16* orow = Out + (size_t)q * DIM + h * HD;
#pragma unroll
  for (int rg = 0; rg < 4; rg++) {
    bf16x4 v0 = {(bf16)(o0[rg * 4] * inv), (bf16)(o0[rg * 4 + 1] * inv),
                 (bf16)(o0[rg * 4 + 2] * inv), (bf16)(o0[rg * 4 + 3] * inv)};
    *(bf16x4*)(orow + 8 * rg + 4 * hi) = v0;
    bf16x4 v1 = {(bf16)(o1[rg * 4] * inv), (bf16)(o1[rg * 4 + 1] * inv),
                 (bf16)(o1[rg * 4 + 2] * inv), (bf16)(o1[rg * 4 + 3] * inv)};
    *(bf16x4*)(orow + 32 + 8 * rg + 4 * hi) = v1;
  }
#pragma unroll
  for (int rg = 0; rg < 2; rg++) {
    bf16x4 v2 = {(bf16)(o2[rg * 4] * inv), (bf16)(o2[rg * 4 + 1] * inv),
                 (bf16)(o2[rg * 4 + 2] * inv), (bf16)(o2[rg * 4 + 3] * inv)};
    *(bf16x4*)(orow + 64 + 8 * rg + 4 * hi) = v2;
  }
}

// --------------------------- launch -----------------------------------------
extern "C" void kernel_launch(void* const* d_in, const int* in_sizes, int n_in,
                              void* d_out, int out_size, void* d_ws,
                              size_t ws_size, hipStream_t stream) {
  const float* x = (const float*)d_in[0];
  const int* cu = (const int*)d_in[1];
  const float* rope = (const float*)d_in[2];
  const float* w_qkv = (const float*)d_in[3];
  const float* b_qkv = (const float*)d_in[4];
  const float* w_proj = (const float*)d_in[5];
  const float* b_proj = (const float*)d_in[6];
  const int nseg = in_sizes[1] - 1;

  bf16* pA = (bf16*)d_ws;                          // S*DIM (dead after gemm256)
  bf16* pB = pA + (size_t)S * DIM;
  bf16* wp16 = pB + (size_t)NQKV * DIM;
  bf16* qkv16 = wp16 + (size_t)DIM * DIM;
  bf16* Qb = qkv16 + (size_t)S * NQKV;             // H*S*80
  bf16* Kb = Qb + (size_t)H * S * HD;              // H*S*128
  bf16* VTb = Kb + (size_t)H * S * KDP;            // H*80*S
  bf16* attn16 = pA;                               // alias dead pA

  const long total_chunks = PA_CHUNKS + PB_CHUNKS + PW_CHUNKS;
  pack_inputs<<<(int)(total_chunks / 256), 256, 0, stream>>>(
      x, w_qkv, w_proj, pA, pB, wp16);
  gemm256<true><<<dim3(NQKV / 256, S / 256), 512, 131072, stream>>>(
      pA, pB, b_qkv, qkv16, S, NQKV, DIM);
  rope_scatter<<<H * 48, 256, 0, stream>>>(qkv16, rope, Qb, Kb, VTb);
  attn_kern<<<H * 24, 256, 0, stream>>>(Qb, Kb, VTb, cu, nseg, attn16);
  gemm_bt<false><<<dim3(DIM / 128, S / 128), 256, 0, stream>>>(
      attn16, wp16, b_proj, d_out, S, DIM, DIM);
}

// Round 7
// 131.327 us; speedup vs baseline: 1.0215x; 1.0084x over previous
//
#include <hip/hip_runtime.h>

// ---------------------------------------------------------------------------
// Attention block, MI355X bf16-MFMA implementation.  R7:
//  - rope_scatter + qkv16 ELIMINATED: gemm256 epilogue applies bias + RoPE
//    (register shfl_xor(1) via interleaved-pair weight permutation) and
//    writes Q/K/VT directly through an LDS bounce (coalesced bf16x8 stores,
//    V transposed in-LDS).
//  - pack_inputs: + w_qkv row permutation (pairs adjacent), + K-pad zeroing,
//    + cos/sin tables [40][S].
//  - attn / proj unchanged.  Pipeline: pack -> gemm256 -> attn -> proj.
// ---------------------------------------------------------------------------

typedef __bf16 bf16;
typedef __bf16 bf16x4 __attribute__((ext_vector_type(4)));
typedef __bf16 bf16x8 __attribute__((ext_vector_type(8)));
typedef float f32x4 __attribute__((ext_vector_type(4)));
typedef float f32x16 __attribute__((ext_vector_type(16)));
typedef unsigned int u32;

constexpr int S = 3072;
constexpr int DIM = 1280;
constexpr int H = 16;
constexpr int HD = 80;
constexpr int KDP = 128;        // K head-dim padded (pow2 rows for swizzle)
constexpr int NQKV = 3 * DIM;   // 3840

constexpr int MB_A = S / 256;    // 12
constexpr int NB_B = NQKV / 256; // 15
constexpr int NKT = DIM / 32;    // 40

// log2(e) / sqrt(80): folded into Q so scores are in exp2 domain.
constexpr float QSCALE = 1.4426950408889634f / 8.94427190999916f;

__device__ __forceinline__ void gload_lds16(const void* g, void* l) {
  __builtin_amdgcn_global_load_lds(
      (const __attribute__((address_space(1))) void*)g,
      (__attribute__((address_space(3))) void*)l, 16, 0, 0);
}

__device__ __forceinline__ u32 pkbf2(float a, float b) {
  union { bf16 h[2]; u32 w; } u;
  u.h[0] = (bf16)a; u.h[1] = (bf16)b;
  return u.w;
}

// V-block LDS swizzle: bank-xor mixes high s-bits so column reads (s=8t+e)
// hit 32 distinct banks.  Byte offset within a 512B row.
__device__ __forceinline__ int swv(int s) {
  return ((((s >> 3) & 31) ^ ((s & 7) << 2)) << 2);
}

// --------------------------- input packing ----------------------------------
// pA[mb][kt]: 16KB LDS image of x; pB[nb][kt]: idem of w_qkv with PERMUTED
// rows (pairs (d,d+40) adjacent: np -> orig row); wp16: linear bf16 w_proj;
// + zero K pad cols [80,128); + cos/sin tables [40][S].
constexpr long PA_CHUNKS = (long)MB_A * NKT * 1024;   // 491520
constexpr long PB_CHUNKS = (long)NB_B * NKT * 1024;   // 614400
constexpr long PW_CHUNKS = (long)DIM * DIM / 8;       // 204800
constexpr long KP_CHUNKS = (long)H * S * 48 / 8;      // 294912
constexpr long CS_CHUNKS = (long)S * 40 / 8;          // 15360
constexpr long TOT_CHUNKS = PA_CHUNKS + PB_CHUNKS + PW_CHUNKS + KP_CHUNKS + CS_CHUNKS;

__global__ __launch_bounds__(256) void pack_inputs(
    const float* __restrict__ x, const float* __restrict__ wq,
    const float* __restrict__ wp, const float* __restrict__ rope,
    bf16* __restrict__ pA, bf16* __restrict__ pB, bf16* __restrict__ wp16,
    bf16* __restrict__ Kb, float* __restrict__ ctab, float* __restrict__ stab) {
  long t = (long)blockIdx.x * 256 + threadIdx.x;
  if (t < PA_CHUNKS + PB_CHUNKS) {
    int blk, rem;
    const float* base;
    bf16* obase;
    bool isB = false;
    if (t < PA_CHUNKS) {
      blk = (int)(t / (NKT * 1024)); rem = (int)(t % (NKT * 1024));
      base = x; obase = pA + t * 8;
    } else {
      long t2 = t - PA_CHUNKS;
      blk = (int)(t2 / (NKT * 1024)); rem = (int)(t2 % (NKT * 1024));
      base = wq; obase = pB + t2 * 8;
      isB = true;
    }
    const int kt = rem >> 10, c = rem & 1023;
    const int lin = c * 16;
    const int logi = lin ^ (((lin >> 7) & 7) << 4);
    int row = logi >> 6;
    const int col = (logi & 63) >> 1;
    int grow = blk * 256 + row;
    if (isB && grow < 2560) {  // permute q/k rows: pairs adjacent
      const int ty = grow / 1280, rm = grow % 1280;
      const int h = rm / 80, p = rm % 80;
      grow = ty * 1280 + h * 80 + (p >> 1) + (p & 1) * 40;
    }
    const float* src = base + (size_t)grow * DIM + kt * 32 + col;
    float4 v0 = *(const float4*)src;
    float4 v1 = *(const float4*)(src + 4);
    bf16x8 o = {(bf16)v0.x, (bf16)v0.y, (bf16)v0.z, (bf16)v0.w,
                (bf16)v1.x, (bf16)v1.y, (bf16)v1.z, (bf16)v1.w};
    *(bf16x8*)obase = o;
  } else if (t < PA_CHUNKS + PB_CHUNKS + PW_CHUNKS) {
    long t2 = t - PA_CHUNKS - PB_CHUNKS;
    const float* src = wp + t2 * 8;
    float4 v0 = *(const float4*)src;
    float4 v1 = *(const float4*)(src + 4);
    bf16x8 o = {(bf16)v0.x, (bf16)v0.y, (bf16)v0.z, (bf16)v0.w,
                (bf16)v1.x, (bf16)v1.y, (bf16)v1.z, (bf16)v1.w};
    *(bf16x8*)(wp16 + t2 * 8) = o;
  } else if (t < PA_CHUNKS + PB_CHUNKS + PW_CHUNKS + KP_CHUNKS) {
    long t2 = t - PA_CHUNKS - PB_CHUNKS - PW_CHUNKS;
    const int h = (int)(t2 / (S * 6)), r = (int)(t2 % (S * 6));
    const int s = r / 6, cc = r % 6;
    bf16x8 z = {};
    *(bf16x8*)(Kb + ((size_t)h * S + s) * KDP + 80 + cc * 8) = z;
  } else {
    long t3 = t - PA_CHUNKS - PB_CHUNKS - PW_CHUNKS - KP_CHUNKS;
#pragma unroll
    for (int k = 0; k < 8; k++) {
      const int idx = (int)(t3 * 8 + k);
      const int s = idx / 40, a = idx % 40;
      float sn, cs;
      __sincosf(rope[idx], &sn, &cs);
      ctab[a * S + s] = cs;
      stab[a * S + s] = sn;
    }
  }
}

// --------------------------- fused QKV GEMM + rope/scatter ------------------
// 256x256 tile, 8 waves, 4-slot ring (as R5).  Epilogue: bias (+rope for Q/K
// via shfl_xor(1) pairs) -> LDS bounce -> coalesced Q/K row writes or V
// in-LDS transpose -> VT.
__global__ __launch_bounds__(512, 2) void gemm256(
    const bf16* __restrict__ pA, const bf16* __restrict__ pB,
    const float* __restrict__ bias, const float* __restrict__ ctab,
    const float* __restrict__ stab, bf16* __restrict__ Qb,
    bf16* __restrict__ Kb, bf16* __restrict__ VTb) {
  extern __shared__ char lds[];  // ring: 4 x 32KB ; epilogue: [256][512B]
  const int tid = threadIdx.x;
  const int w = tid >> 6, lane = tid & 63;
  const int r15 = lane & 15, b4 = lane >> 4;
  const int wr = w >> 2, wc = w & 3;
  const int nwg = gridDim.x * gridDim.y;
  const int orig = blockIdx.y * gridDim.x + blockIdx.x;
  const int xcd = orig % 8, loc = orig / 8;
  const int qq = nwg / 8, rq = nwg % 8;
  const int swzid =
      (xcd < rq ? xcd * (qq + 1) : rq * (qq + 1) + (xcd - rq) * qq) + loc;
  const int nb = swzid % gridDim.x, mb = swzid / gridDim.x;
  const int m0 = mb * 256;
  const char* aPanel = (const char*)pA + (size_t)mb * NKT * 16384;
  const char* bPanel = (const char*)pB + (size_t)nb * NKT * 16384;
  auto stageA = [&](int kt) {
    char* s = lds + (kt & 3) * 32768;
    const char* g = aPanel + (size_t)kt * 16384;
    gload_lds16(g + tid * 16, s + tid * 16);
    gload_lds16(g + 8192 + tid * 16, s + 8192 + tid * 16);
  };
  auto stageB = [&](int kt) {
    char* s = lds + (kt & 3) * 32768 + 16384;
    const char* g = bPanel + (size_t)kt * 16384;
    gload_lds16(g + tid * 16, s + tid * 16);
    gload_lds16(g + 8192 + tid * 16, s + 8192 + tid * 16);
  };
  f32x4 acc[8][4] = {};
  stageA(0); stageB(0); stageA(1); stageB(1); stageA(2); stageB(2);
  asm volatile("s_waitcnt vmcnt(8)" ::: "memory");
  __builtin_amdgcn_s_barrier();
  for (int kt = 0; kt < NKT; ++kt) {
    const char* As = lds + (kt & 3) * 32768;
    const char* Bs = As + 16384;
    const bool pf = (kt + 3 < NKT);
    bf16x8 afr[4], bfr[4];
#pragma unroll
    for (int i = 0; i < 4; i++) {
      int a = (wr * 128 + i * 16 + r15) * 64 + b4 * 16;
      a ^= ((a >> 7) & 7) << 4;
      afr[i] = *(const bf16x8*)(As + a);
    }
#pragma unroll
    for (int j = 0; j < 4; j++) {
      int a = (wc * 64 + j * 16 + r15) * 64 + b4 * 16;
      a ^= ((a >> 7) & 7) << 4;
      bfr[j] = *(const bf16x8*)(Bs + a);
    }
    if (pf) stageA(kt + 3);
    asm volatile("" ::: "memory");
    __builtin_amdgcn_s_barrier();
    __builtin_amdgcn_s_setprio(1);
#pragma unroll
    for (int i = 0; i < 4; i++)
#pragma unroll
      for (int j = 0; j < 4; j++)
        acc[i][j] = __builtin_amdgcn_mfma_f32_16x16x32_bf16(afr[i], bfr[j],
                                                            acc[i][j], 0, 0, 0);
    __builtin_amdgcn_s_setprio(0);
    asm volatile("" ::: "memory");
    __builtin_amdgcn_s_barrier();
#pragma unroll
    for (int i = 0; i < 4; i++) {
      int a = (wr * 128 + 64 + i * 16 + r15) * 64 + b4 * 16;
      a ^= ((a >> 7) & 7) << 4;
      afr[i] = *(const bf16x8*)(As + a);
    }
    if (pf) stageB(kt + 3);
    asm volatile("" ::: "memory");
    __builtin_amdgcn_s_barrier();
    __builtin_amdgcn_s_setprio(1);
#pragma unroll
    for (int i = 0; i < 4; i++)
#pragma unroll
      for (int j = 0; j < 4; j++)
        acc[4 + i][j] = __builtin_amdgcn_mfma_f32_16x16x32_bf16(
            afr[i], bfr[j], acc[4 + i][j], 0, 0, 0);
    __builtin_amdgcn_s_setprio(0);
    const int rem = NKT - 2 - kt;
    if (rem >= 2)      asm volatile("s_waitcnt vmcnt(8)" ::: "memory");
    else if (rem == 1) asm volatile("s_waitcnt vmcnt(4)" ::: "memory");
    else if (rem == 0) asm volatile("s_waitcnt vmcnt(0)" ::: "memory");
    else               asm volatile("" ::: "memory");
    __builtin_amdgcn_s_barrier();
  }
  // ------------------- fused epilogue -------------------
  const int n0 = nb * 256;
  const int type = n0 / 1280;            // 0=Q 1=K 2=V
  const int cpart0 = n0 - type * 1280;   // col base within type
  if (type < 2) {
    // bias + rope in registers, bounce via LDS, coalesced row writes.
#pragma unroll
    for (int j = 0; j < 4; j++) {
      const int c = wc * 64 + j * 16 + r15;
      const int cp = cpart0 + c;
      const int h = cp / 80, p = cp % 80;
      const int d = (p >> 1) + (p & 1) * 40;
      const float bv = bias[type * 1280 + h * 80 + d];
      const int a = p >> 1;
#pragma unroll
      for (int i = 0; i < 8; i++) {
        const int sl = wr * 128 + i * 16 + b4 * 4;
        f32x4 cs4 = *(const f32x4*)&ctab[a * S + m0 + sl];
        f32x4 sn4 = *(const f32x4*)&stab[a * S + m0 + sl];
#pragma unroll
        for (int r = 0; r < 4; r++) {
          float v = acc[i][j][r] + bv;
          float ov = __shfl_xor(v, 1);
          float res = (p & 1) ? (v * cs4[r] + ov * sn4[r])
                              : (v * cs4[r] - ov * sn4[r]);
          if (type == 0) res *= QSCALE;
          *(bf16*)(lds + (sl + r) * 512 + ((2 * c) ^ (((sl + r) & 7) << 4))) =
              (bf16)res;
        }
      }
    }
    __syncthreads();
#pragma unroll
    for (int t = 0; t < 16; t++) {
      const int task = t * 512 + tid;
      const int sl = task >> 5, c = (task & 31) * 8;
      bf16x8 v = *(const bf16x8*)(lds + sl * 512 + ((2 * c) ^ ((sl & 7) << 4)));
      const int cp = cpart0 + c, h = cp / 80, p = cp % 80;
      bf16* dst = type ? Kb + ((size_t)h * S + m0 + sl) * KDP + p
                       : Qb + ((size_t)h * S + m0 + sl) * HD + p;
      *(bf16x8*)dst = v;
    }
  } else {
    // V: bias only, in-LDS transpose -> VT[h][d][s].
#pragma unroll
    for (int j = 0; j < 4; j++) {
      const int c = wc * 64 + j * 16 + r15;
      const float bv = bias[2560 + cpart0 + c];
#pragma unroll
      for (int i = 0; i < 8; i++) {
        const int sl = wr * 128 + i * 16 + b4 * 4;
#pragma unroll
        for (int r = 0; r < 4; r++) {
          *(bf16*)(lds + (sl + r) * 512 + ((2 * c) ^ swv(sl + r))) =
              (bf16)(acc[i][j][r] + bv);
        }
      }
    }
    __syncthreads();
#pragma unroll
    for (int t = 0; t < 16; t++) {
      const int task = t * 512 + tid;
      const int c = task >> 5, s0 = (task & 31) * 8;
      union { bf16 h[8]; bf16x8 v; } o;
#pragma unroll
      for (int e = 0; e < 8; e++)
        o.h[e] = *(const bf16*)(lds + (s0 + e) * 512 + ((2 * c) ^ swv(s0 + e)));
      const int cp = cpart0 + c, h = cp / 80, d = cp % 80;
      *(bf16x8*)(VTb + ((size_t)(h * 80 + d)) * S + m0 + s0) = o.v;
    }
  }
}

// --------------------------- 128^2 2-phase GEMM (proj, unchanged) -----------
template <bool OUT_BF16>
__global__ __launch_bounds__(256) void gemm_bt(
    const bf16* __restrict__ A, const bf16* __restrict__ B,
    const float* __restrict__ bias, void* __restrict__ Cout, int M, int N,
    int K) {
  __shared__ bf16 Al[2][128 * 32];
  __shared__ bf16 Bl[2][128 * 32];
  const int tid = threadIdx.x;
  const int w = tid >> 6, lane = tid & 63;
  const int r15 = lane & 15, b4 = lane >> 4;
  const int nwg = gridDim.x * gridDim.y;
  const int orig = blockIdx.y * gridDim.x + blockIdx.x;
  const int swzid = (orig & 7) * (nwg >> 3) + (orig >> 3);
  const int bx = swzid % gridDim.x, by = swzid / gridDim.x;
  const int m0 = by * 128, n0 = bx * 128;
  const int wm = (w >> 1) * 64, wn = (w & 1) * 64;
  f32x4 acc[4][4] = {};
  const int row0 = tid >> 2, ko0 = (tid & 3) * 8;
  const bf16* Ar0 = A + (size_t)(m0 + row0) * K + ko0;
  const bf16* Ar1 = A + (size_t)(m0 + row0 + 64) * K + ko0;
  const bf16* Br0 = B + (size_t)(n0 + row0) * K + ko0;
  const bf16* Br1 = B + (size_t)(n0 + row0 + 64) * K + ko0;

  auto stage = [&](int buf, int k0) {
    char* la = (char*)Al[buf] + w * 1024;
    char* lb = (char*)Bl[buf] + w * 1024;
    gload_lds16(Ar0 + k0, la);
    gload_lds16(Ar1 + k0, la + 4096);
    gload_lds16(Br0 + k0, lb);
    gload_lds16(Br1 + k0, lb + 4096);
  };

  stage(0, 0);
  int cur = 0;
  for (int k0 = 0; k0 < K; k0 += 32) {
    __syncthreads();
    if (k0 + 32 < K) stage(cur ^ 1, k0 + 32);
    bf16x8 af[4], bfr[4];
#pragma unroll
    for (int i = 0; i < 4; i++) {
      af[i] = *(const bf16x8*)((const char*)Al[cur] + (wm + i * 16 + r15) * 64 + b4 * 16);
      bfr[i] = *(const bf16x8*)((const char*)Bl[cur] + (wn + i * 16 + r15) * 64 + b4 * 16);
    }
#pragma unroll
    for (int i = 0; i < 4; i++)
#pragma unroll
      for (int j = 0; j < 4; j++)
        acc[i][j] = __builtin_amdgcn_mfma_f32_16x16x32_bf16(af[i], bfr[j], acc[i][j], 0, 0, 0);
    cur ^= 1;
  }
#pragma unroll
  for (int j = 0; j < 4; j++) {
    const int n = n0 + wn + j * 16 + r15;
    const float bv = bias[n];
#pragma unroll
    for (int i = 0; i < 4; i++) {
      const int mr = m0 + wm + i * 16 + b4 * 4;
#pragma unroll
      for (int r = 0; r < 4; r++) {
        float v = acc[i][j][r] + bv;
        if (OUT_BF16)
          ((bf16*)Cout)[(size_t)(mr + r) * N + n] = (bf16)v;
        else
          ((float*)Cout)[(size_t)(mr + r) * N + n] = v;
      }
    }
  }
}

// --------------------------- flash attention (32x32, unchanged) -------------
__global__ __launch_bounds__(256) void attn_kern(
    const bf16* __restrict__ Qg, const bf16* __restrict__ Kg,
    const bf16* __restrict__ Vg, const int* __restrict__ cu, int nseg,
    bf16* __restrict__ Out) {
  __shared__ bf16 Kl[2][64 * 128];
  __shared__ bf16 Vl[2][96 * 64];
  const int tid = threadIdx.x, w = tid >> 6, lane = tid & 63;
  const int r31 = lane & 31, hi = lane >> 5;
  const int nwg = gridDim.x;
  const int orig = blockIdx.x;
  const int swzb = (orig & 7) * (nwg >> 3) + (orig >> 3);
  const int h = swzb / 24, qb = swzb % 24;
  const int q = qb * 128 + w * 32 + r31;
  int sq = 0, eq = S, lo = 0, hik = S;
  {
    const int qlo = qb * 128, qhi = qb * 128 + 127;
#pragma unroll
    for (int i = 0; i < 8; i++) {
      if (i >= nseg) break;
      int a = cu[i], b = cu[i + 1];
      if (q >= a && q < b) { sq = a; eq = b; }
      if (qlo >= a && qlo < b) lo = a;
      if (qhi >= a && qhi < b) hik = b;
    }
  }
  {
    int b = tid >> 7, o = (tid & 127) * 16;
    bf16x8 z = {};
    *(bf16x8*)((char*)Vl[b] + 10240 + o) = z;
  }
  bf16x8 qf[5];
  {
    const bf16* qrow = Qg + ((size_t)h * S + q) * HD + hi * 8;
#pragma unroll
    for (int kk = 0; kk < 5; kk++) qf[kk] = *(const bf16x8*)(qrow + kk * 16);
  }
  int kdst[4], ksrc[4], vdst[3], vsrc[3];
#pragma unroll
  for (int c = 0; c < 4; c++) {
    int lin = (c * 256 + tid) * 16;
    int row = lin >> 8, colb = (lin & 255) ^ ((row & 15) << 4);
    kdst[c] = lin; ksrc[c] = row * KDP + colb / 2;
  }
#pragma unroll
  for (int c = 0; c < 3; c++) {
    int lin = (c * 256 + tid) * 16;
    int row = lin >> 7, colb = (lin & 127) ^ ((row & 7) << 4);
    vdst[c] = lin; vsrc[c] = row * S + colb / 2;
  }
  const bf16* Kbase = Kg + (size_t)h * S * KDP;
  const bf16* Vbase = Vg + (size_t)h * HD * S;
  auto stage = [&](int buf, int k0) {
#pragma unroll
    for (int c = 0; c < 4; c++)
      gload_lds16(Kbase + (size_t)k0 * KDP + ksrc[c], (char*)Kl[buf] + kdst[c]);
#pragma unroll
    for (int c = 0; c < 3; c++)
      if (c < 2 || tid < 128)
        gload_lds16(Vbase + vsrc[c] + k0, (char*)Vl[buf] + vdst[c]);
  };
  f32x16 o0 = {}, o1 = {}, o2 = {};
  float m = -1e30f, l = 0.f;
  const int k0s = lo & ~63;
  stage(0, k0s);
  asm volatile("s_waitcnt vmcnt(0)" ::: "memory");
  __syncthreads();
  int cur = 0;
  for (int k0 = k0s; k0 < hik; k0 += 64) {
    const bool more = (k0 + 64 < hik);
    if (more) stage(cur ^ 1, k0 + 64);
    f32x16 st0 = {}, st1 = {};
    __builtin_amdgcn_s_setprio(1);
#pragma unroll
    for (int kk = 0; kk < 5; kk++) {
      const int colb = kk * 32 + hi * 16;
      bf16x8 kf0 = *(const bf16x8*)((const char*)Kl[cur] +
                                    r31 * 256 + (colb ^ ((r31 & 15) << 4)));
      bf16x8 kf1 = *(const bf16x8*)((const char*)Kl[cur] + (32 + r31) * 256 +
                                    (colb ^ ((r31 & 15) << 4)));
      st0 = __builtin_amdgcn_mfma_f32_32x32x16_bf16(kf0, qf[kk], st0, 0, 0, 0);
      st1 = __builtin_amdgcn_mfma_f32_32x32x16_bf16(kf1, qf[kk], st1, 0, 0, 0);
    }
    __builtin_amdgcn_s_setprio(0);
    float tm = -3e38f;
    if (k0 >= sq && k0 + 63 < eq) {
#pragma unroll
      for (int j = 0; j < 16; j++) {
        tm = fmaxf(tm, st0[j]);
        tm = fmaxf(tm, st1[j]);
      }
    } else {
#pragma unroll
      for (int j = 0; j < 16; j++) {
        const int crow = (j & 3) + 8 * (j >> 2) + 4 * hi;
        int key0 = k0 + crow, key1 = k0 + 32 + crow;
        st0[j] = (key0 >= sq && key0 < eq) ? st0[j] : -1e30f;
        st1[j] = (key1 >= sq && key1 < eq) ? st1[j] : -1e30f;
        tm = fmaxf(tm, st0[j]);
        tm = fmaxf(tm, st1[j]);
      }
    }
    tm = fmaxf(tm, __shfl_xor(tm, 32));
    if (!__all(tm <= m + 8.f)) {
      const float mn = fmaxf(m, tm);
      const float alpha = __builtin_amdgcn_exp2f(m - mn);
      o0 *= alpha; o1 *= alpha; o2 *= alpha;
      l *= alpha;
      m = mn;
    }
    float rs = 0.f;
    u32 wd0[4][2], wd1[4][2];
#pragma unroll
    for (int g2 = 0; g2 < 4; g2++) {
#pragma unroll
      for (int hh = 0; hh < 2; hh++) {
        float a0 = __builtin_amdgcn_exp2f(st0[g2 * 4 + 2 * hh] - m);
        float a1 = __builtin_amdgcn_exp2f(st0[g2 * 4 + 2 * hh + 1] - m);
        float b0 = __builtin_amdgcn_exp2f(st1[g2 * 4 + 2 * hh] - m);
        float b1 = __builtin_amdgcn_exp2f(st1[g2 * 4 + 2 * hh + 1] - m);
        rs += a0 + a1 + b0 + b1;
        wd0[g2][hh] = pkbf2(a0, a1);
        wd1[g2][hh] = pkbf2(b0, b1);
      }
    }
    rs += __shfl_xor(rs, 32);
    l += rs;
    __builtin_amdgcn_s_setprio(1);
#pragma unroll
    for (int kk = 0; kk < 4; kk++) {
      const int g2o = (kk & 1) * 2 + hi;
      const int g2s = (kk & 1) * 2 + (hi ^ 1);
      u32 own0, own1, snd0, snd1;
      if (kk < 2) {
        own0 = wd0[g2o][0]; own1 = wd0[g2o][1];
        snd0 = wd0[g2s][0]; snd1 = wd0[g2s][1];
      } else {
        own0 = wd1[g2o][0]; own1 = wd1[g2o][1];
        snd0 = wd1[g2s][0]; snd1 = wd1[g2s][1];
      }
      u32 rc0 = (u32)__shfl_xor((int)snd0, 32);
      u32 rc1 = (u32)__shfl_xor((int)snd1, 32);
      union { u32 w[4]; bf16x8 v; } pf;
      if (hi == 0) { pf.w[0] = own0; pf.w[1] = own1; pf.w[2] = rc0; pf.w[3] = rc1; }
      else         { pf.w[0] = rc0;  pf.w[1] = rc1;  pf.w[2] = own0; pf.w[3] = own1; }
      const int colb = kk * 32 + hi * 16;
#pragma unroll
      for (int mt = 0; mt < 3; mt++) {
        const int row = mt * 32 + r31;
        bf16x8 vf = *(const bf16x8*)((const char*)Vl[cur] + row * 128 +
                                     (colb ^ ((row & 7) << 4)));
        f32x16 * op = mt == 0 ? &o0 : (mt == 1 ? &o1 : &o2);
        *op = __builtin_amdgcn_mfma_f32_32x32x16_bf16(vf, pf.v, *op, 0, 0, 0);
      }
    }
    __builtin_amdgcn_s_setprio(0);
    asm volatile("s_waitcnt vmcnt(0)" ::: "memory");
    __syncthreads();
    cur ^= 1;
  }
  const float inv = 1.f / l;
  bf16* orow = Out + (size_t)q * DIM + h * HD;
#pragma unroll
  for (int rg = 0; rg < 4; rg++) {
    bf16x4 v0 = {(bf16)(o0[rg * 4] * inv), (bf16)(o0[rg * 4 + 1] * inv),
                 (bf16)(o0[rg * 4 + 2] * inv), (bf16)(o0[rg * 4 + 3] * inv)};
    *(bf16x4*)(orow + 8 * rg + 4 * hi) = v0;
    bf16x4 v1 = {(bf16)(o1[rg * 4] * inv), (bf16)(o1[rg * 4 + 1] * inv),
                 (bf16)(o1[rg * 4 + 2] * inv), (bf16)(o1[rg * 4 + 3] * inv)};
    *(bf16x4*)(orow + 32 + 8 * rg + 4 * hi) = v1;
  }
#pragma unroll
  for (int rg = 0; rg < 2; rg++) {
    bf16x4 v2 = {(bf16)(o2[rg * 4] * inv), (bf16)(o2[rg * 4 + 1] * inv),
                 (bf16)(o2[rg * 4 + 2] * inv), (bf16)(o2[rg * 4 + 3] * inv)};
    *(bf16x4*)(orow + 64 + 8 * rg + 4 * hi) = v2;
  }
}

// --------------------------- launch -----------------------------------------
extern "C" void kernel_launch(void* const* d_in, const int* in_sizes, int n_in,
                              void* d_out, int out_size, void* d_ws,
                              size_t ws_size, hipStream_t stream) {
  const float* x = (const float*)d_in[0];
  const int* cu = (const int*)d_in[1];
  const float* rope = (const float*)d_in[2];
  const float* w_qkv = (const float*)d_in[3];
  const float* b_qkv = (const float*)d_in[4];
  const float* w_proj = (const float*)d_in[5];
  const float* b_proj = (const float*)d_in[6];
  const int nseg = in_sizes[1] - 1;

  bf16* pA = (bf16*)d_ws;                          // dead after gemm256
  bf16* pB = pA + (size_t)S * DIM;
  bf16* wp16 = pB + (size_t)NQKV * DIM;
  bf16* Qb = wp16 + (size_t)DIM * DIM;             // H*S*80
  bf16* Kb = Qb + (size_t)H * S * HD;              // H*S*128
  bf16* VTb = Kb + (size_t)H * S * KDP;            // H*80*S
  float* ctab = (float*)(VTb + (size_t)H * HD * S);
  float* stab = ctab + (size_t)S * 40;
  bf16* attn16 = pA;                               // alias dead pA

  pack_inputs<<<(int)(TOT_CHUNKS / 256), 256, 0, stream>>>(
      x, w_qkv, w_proj, rope, pA, pB, wp16, Kb, ctab, stab);
  gemm256<<<dim3(NB_B, MB_A), 512, 131072, stream>>>(
      pA, pB, b_qkv, ctab, stab, Qb, Kb, VTb);
  attn_kern<<<H * 24, 256, 0, stream>>>(Qb, Kb, VTb, cu, nseg, attn16);
  gemm_bt<false><<<dim3(DIM / 128, S / 128), 256, 0, stream>>>(
      attn16, wp16, b_proj, d_out, S, DIM, DIM);
}

// Round 9
// 126.509 us; speedup vs baseline: 1.0604x; 1.0381x over previous
//
#include <hip/hip_runtime.h>

// ---------------------------------------------------------------------------
// Attention block, MI355X bf16-MFMA implementation.  R9 (= R8 + cast fix):
//  - proj GEMM occupancy fix: 64x128 tile (grid 480, ~2 blocks/CU, 7.5
//    waves/CU) replaces 128x128 (grid 240, 1 wave/SIMD, latency-serialized).
//  - pack / gemm256(fused rope) / attn unchanged (isolation).
// ---------------------------------------------------------------------------

typedef __bf16 bf16;
typedef __bf16 bf16x4 __attribute__((ext_vector_type(4)));
typedef __bf16 bf16x8 __attribute__((ext_vector_type(8)));
typedef float f32x4 __attribute__((ext_vector_type(4)));
typedef float f32x16 __attribute__((ext_vector_type(16)));
typedef unsigned int u32;

constexpr int S = 3072;
constexpr int DIM = 1280;
constexpr int H = 16;
constexpr int HD = 80;
constexpr int KDP = 128;        // K head-dim padded (pow2 rows for swizzle)
constexpr int NQKV = 3 * DIM;   // 3840

constexpr int MB_A = S / 256;    // 12
constexpr int NB_B = NQKV / 256; // 15
constexpr int NKT = DIM / 32;    // 40

// log2(e) / sqrt(80): folded into Q so scores are in exp2 domain.
constexpr float QSCALE = 1.4426950408889634f / 8.94427190999916f;

__device__ __forceinline__ void gload_lds16(const void* g, void* l) {
  __builtin_amdgcn_global_load_lds(
      (const __attribute__((address_space(1))) void*)g,
      (__attribute__((address_space(3))) void*)l, 16, 0, 0);
}

__device__ __forceinline__ u32 pkbf2(float a, float b) {
  union { bf16 h[2]; u32 w; } u;
  u.h[0] = (bf16)a; u.h[1] = (bf16)b;
  return u.w;
}

__device__ __forceinline__ int swv(int s) {
  return ((((s >> 3) & 31) ^ ((s & 7) << 2)) << 2);
}

// --------------------------- input packing (unchanged) ----------------------
constexpr long PA_CHUNKS = (long)MB_A * NKT * 1024;   // 491520
constexpr long PB_CHUNKS = (long)NB_B * NKT * 1024;   // 614400
constexpr long PW_CHUNKS = (long)DIM * DIM / 8;       // 204800
constexpr long KP_CHUNKS = (long)H * S * 48 / 8;      // 294912
constexpr long CS_CHUNKS = (long)S * 40 / 8;          // 15360
constexpr long TOT_CHUNKS = PA_CHUNKS + PB_CHUNKS + PW_CHUNKS + KP_CHUNKS + CS_CHUNKS;

__global__ __launch_bounds__(256) void pack_inputs(
    const float* __restrict__ x, const float* __restrict__ wq,
    const float* __restrict__ wp, const float* __restrict__ rope,
    bf16* __restrict__ pA, bf16* __restrict__ pB, bf16* __restrict__ wp16,
    bf16* __restrict__ Kb, float* __restrict__ ctab, float* __restrict__ stab) {
  long t = (long)blockIdx.x * 256 + threadIdx.x;
  if (t < PA_CHUNKS + PB_CHUNKS) {
    int blk, rem;
    const float* base;
    bf16* obase;
    bool isB = false;
    if (t < PA_CHUNKS) {
      blk = (int)(t / (NKT * 1024)); rem = (int)(t % (NKT * 1024));
      base = x; obase = pA + t * 8;
    } else {
      long t2 = t - PA_CHUNKS;
      blk = (int)(t2 / (NKT * 1024)); rem = (int)(t2 % (NKT * 1024));
      base = wq; obase = pB + t2 * 8;
      isB = true;
    }
    const int kt = rem >> 10, c = rem & 1023;
    const int lin = c * 16;
    const int logi = lin ^ (((lin >> 7) & 7) << 4);
    int row = logi >> 6;
    const int col = (logi & 63) >> 1;
    int grow = blk * 256 + row;
    if (isB && grow < 2560) {  // permute q/k rows: pairs adjacent
      const int ty = grow / 1280, rm = grow % 1280;
      const int h = rm / 80, p = rm % 80;
      grow = ty * 1280 + h * 80 + (p >> 1) + (p & 1) * 40;
    }
    const float* src = base + (size_t)grow * DIM + kt * 32 + col;
    float4 v0 = *(const float4*)src;
    float4 v1 = *(const float4*)(src + 4);
    bf16x8 o = {(bf16)v0.x, (bf16)v0.y, (bf16)v0.z, (bf16)v0.w,
                (bf16)v1.x, (bf16)v1.y, (bf16)v1.z, (bf16)v1.w};
    *(bf16x8*)obase = o;
  } else if (t < PA_CHUNKS + PB_CHUNKS + PW_CHUNKS) {
    long t2 = t - PA_CHUNKS - PB_CHUNKS;
    const float* src = wp + t2 * 8;
    float4 v0 = *(const float4*)src;
    float4 v1 = *(const float4*)(src + 4);
    bf16x8 o = {(bf16)v0.x, (bf16)v0.y, (bf16)v0.z, (bf16)v0.w,
                (bf16)v1.x, (bf16)v1.y, (bf16)v1.z, (bf16)v1.w};
    *(bf16x8*)(wp16 + t2 * 8) = o;
  } else if (t < PA_CHUNKS + PB_CHUNKS + PW_CHUNKS + KP_CHUNKS) {
    long t2 = t - PA_CHUNKS - PB_CHUNKS - PW_CHUNKS;
    const int h = (int)(t2 / (S * 6)), r = (int)(t2 % (S * 6));
    const int s = r / 6, cc = r % 6;
    bf16x8 z = {};
    *(bf16x8*)(Kb + ((size_t)h * S + s) * KDP + 80 + cc * 8) = z;
  } else {
    long t3 = t - PA_CHUNKS - PB_CHUNKS - PW_CHUNKS - KP_CHUNKS;
#pragma unroll
    for (int k = 0; k < 8; k++) {
      const int idx = (int)(t3 * 8 + k);
      const int s = idx / 40, a = idx % 40;
      float sn, cs;
      __sincosf(rope[idx], &sn, &cs);
      ctab[a * S + s] = cs;
      stab[a * S + s] = sn;
    }
  }
}

// --------------------------- fused QKV GEMM + rope/scatter (unchanged) ------
__global__ __launch_bounds__(512, 2) void gemm256(
    const bf16* __restrict__ pA, const bf16* __restrict__ pB,
    const float* __restrict__ bias, const float* __restrict__ ctab,
    const float* __restrict__ stab, bf16* __restrict__ Qb,
    bf16* __restrict__ Kb, bf16* __restrict__ VTb) {
  extern __shared__ char lds[];
  const int tid = threadIdx.x;
  const int w = tid >> 6, lane = tid & 63;
  const int r15 = lane & 15, b4 = lane >> 4;
  const int wr = w >> 2, wc = w & 3;
  const int nwg = gridDim.x * gridDim.y;
  const int orig = blockIdx.y * gridDim.x + blockIdx.x;
  const int xcd = orig % 8, loc = orig / 8;
  const int qq = nwg / 8, rq = nwg % 8;
  const int swzid =
      (xcd < rq ? xcd * (qq + 1) : rq * (qq + 1) + (xcd - rq) * qq) + loc;
  const int nb = swzid % gridDim.x, mb = swzid / gridDim.x;
  const int m0 = mb * 256;
  const char* aPanel = (const char*)pA + (size_t)mb * NKT * 16384;
  const char* bPanel = (const char*)pB + (size_t)nb * NKT * 16384;
  auto stageA = [&](int kt) {
    char* s = lds + (kt & 3) * 32768;
    const char* g = aPanel + (size_t)kt * 16384;
    gload_lds16(g + tid * 16, s + tid * 16);
    gload_lds16(g + 8192 + tid * 16, s + 8192 + tid * 16);
  };
  auto stageB = [&](int kt) {
    char* s = lds + (kt & 3) * 32768 + 16384;
    const char* g = bPanel + (size_t)kt * 16384;
    gload_lds16(g + tid * 16, s + tid * 16);
    gload_lds16(g + 8192 + tid * 16, s + 8192 + tid * 16);
  };
  f32x4 acc[8][4] = {};
  stageA(0); stageB(0); stageA(1); stageB(1); stageA(2); stageB(2);
  asm volatile("s_waitcnt vmcnt(8)" ::: "memory");
  __builtin_amdgcn_s_barrier();
  for (int kt = 0; kt < NKT; ++kt) {
    const char* As = lds + (kt & 3) * 32768;
    const char* Bs = As + 16384;
    const bool pf = (kt + 3 < NKT);
    bf16x8 afr[4], bfr[4];
#pragma unroll
    for (int i = 0; i < 4; i++) {
      int a = (wr * 128 + i * 16 + r15) * 64 + b4 * 16;
      a ^= ((a >> 7) & 7) << 4;
      afr[i] = *(const bf16x8*)(As + a);
    }
#pragma unroll
    for (int j = 0; j < 4; j++) {
      int a = (wc * 64 + j * 16 + r15) * 64 + b4 * 16;
      a ^= ((a >> 7) & 7) << 4;
      bfr[j] = *(const bf16x8*)(Bs + a);
    }
    if (pf) stageA(kt + 3);
    asm volatile("" ::: "memory");
    __builtin_amdgcn_s_barrier();
    __builtin_amdgcn_s_setprio(1);
#pragma unroll
    for (int i = 0; i < 4; i++)
#pragma unroll
      for (int j = 0; j < 4; j++)
        acc[i][j] = __builtin_amdgcn_mfma_f32_16x16x32_bf16(afr[i], bfr[j],
                                                            acc[i][j], 0, 0, 0);
    __builtin_amdgcn_s_setprio(0);
    asm volatile("" ::: "memory");
    __builtin_amdgcn_s_barrier();
#pragma unroll
    for (int i = 0; i < 4; i++) {
      int a = (wr * 128 + 64 + i * 16 + r15) * 64 + b4 * 16;
      a ^= ((a >> 7) & 7) << 4;
      afr[i] = *(const bf16x8*)(As + a);
    }
    if (pf) stageB(kt + 3);
    asm volatile("" ::: "memory");
    __builtin_amdgcn_s_barrier();
    __builtin_amdgcn_s_setprio(1);
#pragma unroll
    for (int i = 0; i < 4; i++)
#pragma unroll
      for (int j = 0; j < 4; j++)
        acc[4 + i][j] = __builtin_amdgcn_mfma_f32_16x16x32_bf16(
            afr[i], bfr[j], acc[4 + i][j], 0, 0, 0);
    __builtin_amdgcn_s_setprio(0);
    const int rem = NKT - 2 - kt;
    if (rem >= 2)      asm volatile("s_waitcnt vmcnt(8)" ::: "memory");
    else if (rem == 1) asm volatile("s_waitcnt vmcnt(4)" ::: "memory");
    else if (rem == 0) asm volatile("s_waitcnt vmcnt(0)" ::: "memory");
    else               asm volatile("" ::: "memory");
    __builtin_amdgcn_s_barrier();
  }
  // ------------------- fused epilogue -------------------
  const int n0 = nb * 256;
  const int type = n0 / 1280;            // 0=Q 1=K 2=V
  const int cpart0 = n0 - type * 1280;
  if (type < 2) {
#pragma unroll
    for (int j = 0; j < 4; j++) {
      const int c = wc * 64 + j * 16 + r15;
      const int cp = cpart0 + c;
      const int h = cp / 80, p = cp % 80;
      const int d = (p >> 1) + (p & 1) * 40;
      const float bv = bias[type * 1280 + h * 80 + d];
      const int a = p >> 1;
#pragma unroll
      for (int i = 0; i < 8; i++) {
        const int sl = wr * 128 + i * 16 + b4 * 4;
        f32x4 cs4 = *(const f32x4*)&ctab[a * S + m0 + sl];
        f32x4 sn4 = *(const f32x4*)&stab[a * S + m0 + sl];
#pragma unroll
        for (int r = 0; r < 4; r++) {
          float v = acc[i][j][r] + bv;
          float ov = __shfl_xor(v, 1);
          float res = (p & 1) ? (v * cs4[r] + ov * sn4[r])
                              : (v * cs4[r] - ov * sn4[r]);
          if (type == 0) res *= QSCALE;
          *(bf16*)(lds + (sl + r) * 512 + ((2 * c) ^ (((sl + r) & 7) << 4))) =
              (bf16)res;
        }
      }
    }
    __syncthreads();
#pragma unroll
    for (int t = 0; t < 16; t++) {
      const int task = t * 512 + tid;
      const int sl = task >> 5, c = (task & 31) * 8;
      bf16x8 v = *(const bf16x8*)(lds + sl * 512 + ((2 * c) ^ ((sl & 7) << 4)));
      const int cp = cpart0 + c, h = cp / 80, p = cp % 80;
      bf16* dst = type ? Kb + ((size_t)h * S + m0 + sl) * KDP + p
                       : Qb + ((size_t)h * S + m0 + sl) * HD + p;
      *(bf16x8*)dst = v;
    }
  } else {
#pragma unroll
    for (int j = 0; j < 4; j++) {
      const int c = wc * 64 + j * 16 + r15;
      const float bv = bias[2560 + cpart0 + c];
#pragma unroll
      for (int i = 0; i < 8; i++) {
        const int sl = wr * 128 + i * 16 + b4 * 4;
#pragma unroll
        for (int r = 0; r < 4; r++) {
          *(bf16*)(lds + (sl + r) * 512 + ((2 * c) ^ swv(sl + r))) =
              (bf16)(acc[i][j][r] + bv);
        }
      }
    }
    __syncthreads();
#pragma unroll
    for (int t = 0; t < 16; t++) {
      const int task = t * 512 + tid;
      const int c = task >> 5, s0 = (task & 31) * 8;
      union { bf16 h[8]; bf16x8 v; } o;
#pragma unroll
      for (int e = 0; e < 8; e++)
        o.h[e] = *(const bf16*)(lds + (s0 + e) * 512 + ((2 * c) ^ swv(s0 + e)));
      const int cp = cpart0 + c, h = cp / 80, d = cp % 80;
      *(bf16x8*)(VTb + ((size_t)(h * 80 + d)) * S + m0 + s0) = o.v;
    }
  }
}

// --------------------------- proj GEMM: 64x128 tile, 2-phase ----------------
// C[m][n] = sum_k A[m][k]*B[n][k] + bias[n], fp32 out.  Grid 48x10 = 480
// blocks (~2/CU, 7.5 waves/CU) fixes the 1-wave/SIMD serialization of the
// 128^2 version.  4 waves: wave w owns 32(m) x 64(n).
__global__ __launch_bounds__(256) void gemm_proj(
    const bf16* __restrict__ A, const bf16* __restrict__ B,
    const float* __restrict__ bias, float* __restrict__ Cout, int M, int N,
    int K) {
  __shared__ bf16 Al[2][64 * 32];
  __shared__ bf16 Bl[2][128 * 32];
  const int tid = threadIdx.x;
  const int w = tid >> 6, lane = tid & 63;
  const int r15 = lane & 15, b4 = lane >> 4;
  const int nwg = gridDim.x * gridDim.y;  // 480, %8==0
  const int orig = blockIdx.y * gridDim.x + blockIdx.x;
  const int swzid = (orig & 7) * (nwg >> 3) + (orig >> 3);
  const int bx = swzid % gridDim.x, by = swzid / gridDim.x;
  const int m0 = by * 64, n0 = bx * 128;
  const int wm = (w >> 1) * 32, wn = (w & 1) * 64;
  f32x4 acc[2][4] = {};
  const int row0 = tid >> 2, ko0 = (tid & 3) * 8;
  const bf16* Ar = A + (size_t)(m0 + row0) * K + ko0;    // 64 rows
  const bf16* Br0 = B + (size_t)(n0 + row0) * K + ko0;   // 128 rows
  const bf16* Br1 = B + (size_t)(n0 + row0 + 64) * K + ko0;

  auto stage = [&](int buf, int k0) {
    gload_lds16(Ar + k0, (char*)Al[buf] + tid * 16);
    gload_lds16(Br0 + k0, (char*)Bl[buf] + tid * 16);
    gload_lds16(Br1 + k0, (char*)Bl[buf] + 4096 + tid * 16);
  };

  stage(0, 0);
  int cur = 0;
  for (int k0 = 0; k0 < K; k0 += 32) {
    __syncthreads();
    if (k0 + 32 < K) stage(cur ^ 1, k0 + 32);
    bf16x8 af[2], bfr[4];
#pragma unroll
    for (int i = 0; i < 2; i++)
      af[i] = *(const bf16x8*)((const char*)Al[cur] + (wm + i * 16 + r15) * 64 + b4 * 16);
#pragma unroll
    for (int j = 0; j < 4; j++)
      bfr[j] = *(const bf16x8*)((const char*)Bl[cur] + (wn + j * 16 + r15) * 64 + b4 * 16);
#pragma unroll
    for (int i = 0; i < 2; i++)
#pragma unroll
      for (int j = 0; j < 4; j++)
        acc[i][j] = __builtin_amdgcn_mfma_f32_16x16x32_bf16(af[i], bfr[j], acc[i][j], 0, 0, 0);
    cur ^= 1;
  }
#pragma unroll
  for (int j = 0; j < 4; j++) {
    const int n = n0 + wn + j * 16 + r15;
    const float bv = bias[n];
#pragma unroll
    for (int i = 0; i < 2; i++) {
      const int mr = m0 + wm + i * 16 + b4 * 4;
#pragma unroll
      for (int r = 0; r < 4; r++)
        Cout[(size_t)(mr + r) * N + n] = acc[i][j][r] + bv;
    }
  }
}

// --------------------------- flash attention (32x32, unchanged) -------------
__global__ __launch_bounds__(256) void attn_kern(
    const bf16* __restrict__ Qg, const bf16* __restrict__ Kg,
    const bf16* __restrict__ Vg, const int* __restrict__ cu, int nseg,
    bf16* __restrict__ Out) {
  __shared__ bf16 Kl[2][64 * 128];
  __shared__ bf16 Vl[2][96 * 64];
  const int tid = threadIdx.x, w = tid >> 6, lane = tid & 63;
  const int r31 = lane & 31, hi = lane >> 5;
  const int nwg = gridDim.x;
  const int orig = blockIdx.x;
  const int swzb = (orig & 7) * (nwg >> 3) + (orig >> 3);
  const int h = swzb / 24, qb = swzb % 24;
  const int q = qb * 128 + w * 32 + r31;
  int sq = 0, eq = S, lo = 0, hik = S;
  {
    const int qlo = qb * 128, qhi = qb * 128 + 127;
#pragma unroll
    for (int i = 0; i < 8; i++) {
      if (i >= nseg) break;
      int a = cu[i], b = cu[i + 1];
      if (q >= a && q < b) { sq = a; eq = b; }
      if (qlo >= a && qlo < b) lo = a;
      if (qhi >= a && qhi < b) hik = b;
    }
  }
  {
    int b = tid >> 7, o = (tid & 127) * 16;
    bf16x8 z = {};
    *(bf16x8*)((char*)Vl[b] + 10240 + o) = z;
  }
  bf16x8 qf[5];
  {
    const bf16* qrow = Qg + ((size_t)h * S + q) * HD + hi * 8;
#pragma unroll
    for (int kk = 0; kk < 5; kk++) qf[kk] = *(const bf16x8*)(qrow + kk * 16);
  }
  int kdst[4], ksrc[4], vdst[3], vsrc[3];
#pragma unroll
  for (int c = 0; c < 4; c++) {
    int lin = (c * 256 + tid) * 16;
    int row = lin >> 8, colb = (lin & 255) ^ ((row & 15) << 4);
    kdst[c] = lin; ksrc[c] = row * KDP + colb / 2;
  }
#pragma unroll
  for (int c = 0; c < 3; c++) {
    int lin = (c * 256 + tid) * 16;
    int row = lin >> 7, colb = (lin & 127) ^ ((row & 7) << 4);
    vdst[c] = lin; vsrc[c] = row * S + colb / 2;
  }
  const bf16* Kbase = Kg + (size_t)h * S * KDP;
  const bf16* Vbase = Vg + (size_t)h * HD * S;
  auto stage = [&](int buf, int k0) {
#pragma unroll
    for (int c = 0; c < 4; c++)
      gload_lds16(Kbase + (size_t)k0 * KDP + ksrc[c], (char*)Kl[buf] + kdst[c]);
#pragma unroll
    for (int c = 0; c < 3; c++)
      if (c < 2 || tid < 128)
        gload_lds16(Vbase + vsrc[c] + k0, (char*)Vl[buf] + vdst[c]);
  };
  f32x16 o0 = {}, o1 = {}, o2 = {};
  float m = -1e30f, l = 0.f;
  const int k0s = lo & ~63;
  stage(0, k0s);
  asm volatile("s_waitcnt vmcnt(0)" ::: "memory");
  __syncthreads();
  int cur = 0;
  for (int k0 = k0s; k0 < hik; k0 += 64) {
    const bool more = (k0 + 64 < hik);
    if (more) stage(cur ^ 1, k0 + 64);
    f32x16 st0 = {}, st1 = {};
    __builtin_amdgcn_s_setprio(1);
#pragma unroll
    for (int kk = 0; kk < 5; kk++) {
      const int colb = kk * 32 + hi * 16;
      bf16x8 kf0 = *(const bf16x8*)((const char*)Kl[cur] +
                                    r31 * 256 + (colb ^ ((r31 & 15) << 4)));
      bf16x8 kf1 = *(const bf16x8*)((const char*)Kl[cur] + (32 + r31) * 256 +
                                    (colb ^ ((r31 & 15) << 4)));
      st0 = __builtin_amdgcn_mfma_f32_32x32x16_bf16(kf0, qf[kk], st0, 0, 0, 0);
      st1 = __builtin_amdgcn_mfma_f32_32x32x16_bf16(kf1, qf[kk], st1, 0, 0, 0);
    }
    __builtin_amdgcn_s_setprio(0);
    float tm = -3e38f;
    if (k0 >= sq && k0 + 63 < eq) {
#pragma unroll
      for (int j = 0; j < 16; j++) {
        tm = fmaxf(tm, st0[j]);
        tm = fmaxf(tm, st1[j]);
      }
    } else {
#pragma unroll
      for (int j = 0; j < 16; j++) {
        const int crow = (j & 3) + 8 * (j >> 2) + 4 * hi;
        int key0 = k0 + crow, key1 = k0 + 32 + crow;
        st0[j] = (key0 >= sq && key0 < eq) ? st0[j] : -1e30f;
        st1[j] = (key1 >= sq && key1 < eq) ? st1[j] : -1e30f;
        tm = fmaxf(tm, st0[j]);
        tm = fmaxf(tm, st1[j]);
      }
    }
    tm = fmaxf(tm, __shfl_xor(tm, 32));
    if (!__all(tm <= m + 8.f)) {
      const float mn = fmaxf(m, tm);
      const float alpha = __builtin_amdgcn_exp2f(m - mn);
      o0 *= alpha; o1 *= alpha; o2 *= alpha;
      l *= alpha;
      m = mn;
    }
    float rs = 0.f;
    u32 wd0[4][2], wd1[4][2];
#pragma unroll
    for (int g2 = 0; g2 < 4; g2++) {
#pragma unroll
      for (int hh = 0; hh < 2; hh++) {
        float a0 = __builtin_amdgcn_exp2f(st0[g2 * 4 + 2 * hh] - m);
        float a1 = __builtin_amdgcn_exp2f(st0[g2 * 4 + 2 * hh + 1] - m);
        float b0 = __builtin_amdgcn_exp2f(st1[g2 * 4 + 2 * hh] - m);
        float b1 = __builtin_amdgcn_exp2f(st1[g2 * 4 + 2 * hh + 1] - m);
        rs += a0 + a1 + b0 + b1;
        wd0[g2][hh] = pkbf2(a0, a1);
        wd1[g2][hh] = pkbf2(b0, b1);
      }
    }
    rs += __shfl_xor(rs, 32);
    l += rs;
    __builtin_amdgcn_s_setprio(1);
#pragma unroll
    for (int kk = 0; kk < 4; kk++) {
      const int g2o = (kk & 1) * 2 + hi;
      const int g2s = (kk & 1) * 2 + (hi ^ 1);
      u32 own0, own1, snd0, snd1;
      if (kk < 2) {
        own0 = wd0[g2o][0]; own1 = wd0[g2o][1];
        snd0 = wd0[g2s][0]; snd1 = wd0[g2s][1];
      } else {
        own0 = wd1[g2o][0]; own1 = wd1[g2o][1];
        snd0 = wd1[g2s][0]; snd1 = wd1[g2s][1];
      }
      u32 rc0 = (u32)__shfl_xor((int)snd0, 32);
      u32 rc1 = (u32)__shfl_xor((int)snd1, 32);
      union { u32 w[4]; bf16x8 v; } pf;
      if (hi == 0) { pf.w[0] = own0; pf.w[1] = own1; pf.w[2] = rc0; pf.w[3] = rc1; }
      else         { pf.w[0] = rc0;  pf.w[1] = rc1;  pf.w[2] = own0; pf.w[3] = own1; }
      const int colb = kk * 32 + hi * 16;
#pragma unroll
      for (int mt = 0; mt < 3; mt++) {
        const int row = mt * 32 + r31;
        bf16x8 vf = *(const bf16x8*)((const char*)Vl[cur] + row * 128 +
                                     (colb ^ ((row & 7) << 4)));
        f32x16 * op = mt == 0 ? &o0 : (mt == 1 ? &o1 : &o2);
        *op = __builtin_amdgcn_mfma_f32_32x32x16_bf16(vf, pf.v, *op, 0, 0, 0);
      }
    }
    __builtin_amdgcn_s_setprio(0);
    asm volatile("s_waitcnt vmcnt(0)" ::: "memory");
    __syncthreads();
    cur ^= 1;
  }
  const float inv = 1.f / l;
  bf16* orow = Out + (size_t)q * DIM + h * HD;
#pragma unroll
  for (int rg = 0; rg < 4; rg++) {
    bf16x4 v0 = {(bf16)(o0[rg * 4] * inv), (bf16)(o0[rg * 4 + 1] * inv),
                 (bf16)(o0[rg * 4 + 2] * inv), (bf16)(o0[rg * 4 + 3] * inv)};
    *(bf16x4*)(orow + 8 * rg + 4 * hi) = v0;
    bf16x4 v1 = {(bf16)(o1[rg * 4] * inv), (bf16)(o1[rg * 4 + 1] * inv),
                 (bf16)(o1[rg * 4 + 2] * inv), (bf16)(o1[rg * 4 + 3] * inv)};
    *(bf16x4*)(orow + 32 + 8 * rg + 4 * hi) = v1;
  }
#pragma unroll
  for (int rg = 0; rg < 2; rg++) {
    bf16x4 v2 = {(bf16)(o2[rg * 4] * inv), (bf16)(o2[rg * 4 + 1] * inv),
                 (bf16)(o2[rg * 4 + 2] * inv), (bf16)(o2[rg * 4 + 3] * inv)};
    *(bf16x4*)(orow + 64 + 8 * rg + 4 * hi) = v2;
  }
}

// --------------------------- launch -----------------------------------------
extern "C" void kernel_launch(void* const* d_in, const int* in_sizes, int n_in,
                              void* d_out, int out_size, void* d_ws,
                              size_t ws_size, hipStream_t stream) {
  const float* x = (const float*)d_in[0];
  const int* cu = (const int*)d_in[1];
  const float* rope = (const float*)d_in[2];
  const float* w_qkv = (const float*)d_in[3];
  const float* b_qkv = (const float*)d_in[4];
  const float* w_proj = (const float*)d_in[5];
  const float* b_proj = (const float*)d_in[6];
  const int nseg = in_sizes[1] - 1;

  bf16* pA = (bf16*)d_ws;                          // dead after gemm256
  bf16* pB = pA + (size_t)S * DIM;
  bf16* wp16 = pB + (size_t)NQKV * DIM;
  bf16* Qb = wp16 + (size_t)DIM * DIM;             // H*S*80
  bf16* Kb = Qb + (size_t)H * S * HD;              // H*S*128
  bf16* VTb = Kb + (size_t)H * S * KDP;            // H*80*S
  float* ctab = (float*)(VTb + (size_t)H * HD * S);
  float* stab = ctab + (size_t)S * 40;
  bf16* attn16 = pA;                               // alias dead pA

  pack_inputs<<<(int)(TOT_CHUNKS / 256), 256, 0, stream>>>(
      x, w_qkv, w_proj, rope, pA, pB, wp16, Kb, ctab, stab);
  gemm256<<<dim3(NB_B, MB_A), 512, 131072, stream>>>(
      pA, pB, b_qkv, ctab, stab, Qb, Kb, VTb);
  attn_kern<<<H * 24, 256, 0, stream>>>(Qb, Kb, VTb, cu, nseg, attn16);
  gemm_proj<<<dim3(DIM / 128, S / 64), 256, 0, stream>>>(
      attn16, wp16, b_proj, (float*)d_out, S, DIM, DIM);
}